// Round 4
// baseline (1939.015 us; speedup 1.0000x reference)
//
#include <hip/hip_runtime.h>

#define T_LEN 4096

typedef float v2f __attribute__((ext_vector_type(2)));
typedef float v4f __attribute__((ext_vector_type(4)));

__device__ __forceinline__ float frcp(float x) { return __builtin_amdgcn_rcpf(x); }
__device__ __forceinline__ float fexp2(float x) { return __builtin_amdgcn_exp2f(x); }

// packed dual-FMA: acc = w*s + acc (VOP3P, full-rate fp32 pairs, all-VGPR).
__device__ __forceinline__ void pk_fma_v(v2f& acc, v2f w, v2f s) {
  asm("v_pk_fma_f32 %0, %1, %2, %0" : "+v"(acc) : "v"(w), "v"(s));
}

// quad_perm DPP butterfly adds: xor1 = 0xB1, xor2 = 0x4E
template <int CTRL>
__device__ __forceinline__ float dpp_add(float x) {
  int t = __builtin_amdgcn_mov_dpp(__float_as_int(x), CTRL, 0xF, 0xF, true);
  return x + __int_as_float(t);
}

// compile-time fence: forbids reordering LDS publish vs dependent broadcast
// reads (float stores vs v4f reinterpret loads could be TBAA-noalias).
__device__ __forceinline__ void cfence() { asm volatile("" ::: "memory"); }

#define NLN2f (-0.6931471805599453f)

// readout: y[0..15] lives in cb[64..79]; all lanes compute (uniform), lane 0 stores.
__device__ __forceinline__ float readout_lds(const float* cb,
                                             const float* __restrict__ rW,
                                             float rb0) {
  v4f a = *(const v4f*)(cb + 64);
  v4f b = *(const v4f*)(cb + 68);
  v4f c = *(const v4f*)(cb + 72);
  v4f d = *(const v4f*)(cb + 76);
  float o = rb0;
  o = fmaf(rW[0],  a.x, o); o = fmaf(rW[1],  a.y, o);
  o = fmaf(rW[2],  a.z, o); o = fmaf(rW[3],  a.w, o);
  o = fmaf(rW[4],  b.x, o); o = fmaf(rW[5],  b.y, o);
  o = fmaf(rW[6],  b.z, o); o = fmaf(rW[7],  b.w, o);
  o = fmaf(rW[8],  c.x, o); o = fmaf(rW[9],  c.y, o);
  o = fmaf(rW[10], c.z, o); o = fmaf(rW[11], c.w, o);
  o = fmaf(rW[12], d.x, o); o = fmaf(rW[13], d.y, o);
  o = fmaf(rW[14], d.z, o); o = fmaf(rW[15], d.w, o);
  return o;
}

// One wave (64 lanes) per TWO batch elements; block = 1 wave => no barriers.
// Structure identical to the verified single-element LDS-broadcast kernel,
// duplicated per element and statement-interleaved: the two recurrences are
// independent dependency chains, so chain B's VALU work fills chain A's
// ds_read/transcendental latency stalls (no readlane->SGPR hazards remain
// to serialize the wave). Weights are shared in VGPRs; each element has its
// own cbuf/xbuf LDS regions.
__global__ __launch_bounds__(64) void disc_kernel(
    const float* __restrict__ ts, const float* __restrict__ ys,
    const float* __restrict__ iW1, const float* __restrict__ ib1,
    const float* __restrict__ iW2, const float* __restrict__ ib2,
    const float* __restrict__ vW1, const float* __restrict__ vb1,
    const float* __restrict__ vW2, const float* __restrict__ vb2,
    const float* __restrict__ cW1, const float* __restrict__ cb1,
    const float* __restrict__ cW2, const float* __restrict__ cb2,
    const float* __restrict__ rW, const float* __restrict__ rb,
    float* __restrict__ out)
{
  const int b0  = blockIdx.x * 2;
  const int l   = threadIdx.x;
  const int h16 = l & 15;
  const int p   = (l >> 4) & 1;
  const int hf  = l >> 2;
  const int d0  = (2 * l) & 7;
  const int q4  = 4 * (l & 3);        // f-quartet base (s_f columns)
  const int ywslot = ((l & 3) == 0) ? (64 + hf) : (80 + l);  // y write / dump

  __shared__ __align__(16) float sbuf0[16];    // init relu staging
  __shared__ __align__(16) float sbuf1[16];
  __shared__ __align__(16) float cbuf0[160];   // [0..63] s, [64..79] y, [80..143] dump
  __shared__ __align__(16) float cbuf1[160];
  __shared__ __align__(16) float xbuf0[1024];  // 2 x 64 dx-rows (8 floats each)
  __shared__ __align__(16) float xbuf1[1024];

  const float* __restrict__ ysb0 = ys + (size_t)b0 * (T_LEN * 8);
  const float* __restrict__ ysb1 = ysb0 + (size_t)(T_LEN * 8);

  const float NL2E = -1.4426950408889634f;                 // -log2(e)
  const float TSW  = 2.0f * 1.4426950408889634f * 0.909f;  // weight scale (tanh arg)
  const float TSB  = 2.0f * 1.4426950408889634f;           // bias scale (tanh arg)

  // ---- per-lane weights (scaled), shared by both elements ----
  float w1t, b1m;
  v2f W1y2[8];
  {
    const float* W1 = p ? cW1 : vW1;
    const float* bv = p ? cb1 : vb1;
    w1t = NL2E * W1[h16 * 17];
    b1m = NL2E * bv[h16];
#pragma unroll
    for (int k = 0; k < 8; ++k) {
      v2f w; w.x = NL2E * W1[h16 * 17 + 1 + 2 * k];
             w.y = NL2E * W1[h16 * 17 + 2 + 2 * k];
      W1y2[k] = w;
    }
  }
  v2f W2q[2];
#pragma unroll
  for (int j = 0; j < 2; ++j) {
    v2f w; w.x = TSW * vW2[hf * 16 + q4 + 2 * j];
           w.y = TSW * vW2[hf * 16 + q4 + 2 * j + 1];
    W2q[j] = w;
  }
  v2f G0p[8], G1p[8];
#pragma unroll
  for (int k = 0; k < 8; ++k) {
    v2f c0; c0.x = TSW * cW2[(2 * l) * 16 + 2 * k]; c0.y = TSW * cW2[(2 * l) * 16 + 2 * k + 1];
    G0p[k] = c0;
    v2f c1; c1.x = TSW * cW2[(2 * l + 1) * 16 + 2 * k]; c1.y = TSW * cW2[(2 * l + 1) * 16 + 2 * k + 1];
    G1p[k] = c1;
  }
  const float b2p  = TSB * vb2[hf];
  const float bg0p = TSB * cb2[2 * l];
  const float bg1p = TSB * cb2[2 * l + 1];

  const float t0 = ts[0];

  // ---- initial hidden states (cold path, via LDS; same-wave DS is ordered) ----
  float y_own0, y_own1;
  {
    float a0 = ib1[h16] + iW1[h16 * 9] * t0;
    float a1 = a0;
#pragma unroll
    for (int d = 0; d < 8; ++d) {
      const float w = iW1[h16 * 9 + 1 + d];
      a0 = fmaf(w, ysb0[d], a0);
      a1 = fmaf(w, ysb1[d], a1);
    }
    sbuf0[h16] = fmaxf(a0, 0.0f);
    sbuf1[h16] = fmaxf(a1, 0.0f);
    cfence();
    float c0 = ib2[h16];
    float c1 = ib2[h16];
#pragma unroll
    for (int k = 0; k < 16; ++k) {
      const float w = iW2[h16 * 16 + k];
      c0 = fmaf(w, sbuf0[k], c0);
      c1 = fmaf(w, sbuf1[k], c1);
    }
    cbuf0[64 + h16] = c0;     // duplicate same-addr same-value writes (init only)
    cbuf1[64 + h16] = c1;
    cfence();
    y_own0 = cbuf0[64 + hf];
    y_own1 = cbuf1[64 + hf];
  }

  // ---- readout at t0 ----
  {
    const float rb0 = rb[0];
    const float o0 = readout_lds(cbuf0, rW, rb0);
    const float o1 = readout_lds(cbuf1, rW, rb0);
    if (l == 0) {
      out[2 * b0]     = o0;
      out[2 * b0 + 2] = o1;
    }
  }

  // ---- dx staging: 64-row chunks, double-buffered, prefetch next chunk ----
  const int CLAMP = T_LEN * 8 - 4;
  float4 A0, B0, C0, D0, A1, B1, C1, D1;
  {
    const int f0 = l * 8;
    A0 = *(const float4*)(ysb0 + min(f0,      CLAMP));
    B0 = *(const float4*)(ysb0 + min(f0 + 4,  CLAMP));
    C0 = *(const float4*)(ysb0 + min(f0 + 8,  CLAMP));
    D0 = *(const float4*)(ysb0 + min(f0 + 12, CLAMP));
    A1 = *(const float4*)(ysb1 + min(f0,      CLAMP));
    B1 = *(const float4*)(ysb1 + min(f0 + 4,  CLAMP));
    C1 = *(const float4*)(ysb1 + min(f0 + 8,  CLAMP));
    D1 = *(const float4*)(ysb1 + min(f0 + 12, CLAMP));
    float4 e0, e1;
    e0.x = C0.x - A0.x; e0.y = C0.y - A0.y; e0.z = C0.z - A0.z; e0.w = C0.w - A0.w;
    e1.x = D0.x - B0.x; e1.y = D0.y - B0.y; e1.z = D0.z - B0.z; e1.w = D0.w - B0.w;
    *(float4*)(xbuf0 + l * 8)     = e0;
    *(float4*)(xbuf0 + l * 8 + 4) = e1;
    e0.x = C1.x - A1.x; e0.y = C1.y - A1.y; e0.z = C1.z - A1.z; e0.w = C1.w - A1.w;
    e1.x = D1.x - B1.x; e1.y = D1.y - B1.y; e1.z = D1.z - B1.z; e1.w = D1.w - B1.w;
    *(float4*)(xbuf1 + l * 8)     = e0;
    *(float4*)(xbuf1 + l * 8 + 4) = e1;
    cfence();
  }

  float t = t0;
  for (int c = 0; c < 64; ++c) {
    // prefetch chunk c+1 for both elements (clamped; last chunk re-reads itself)
    {
      const int cn = min(c + 1, 63);
      const int f0 = cn * 512 + l * 8;
      A0 = *(const float4*)(ysb0 + min(f0,      CLAMP));
      B0 = *(const float4*)(ysb0 + min(f0 + 4,  CLAMP));
      C0 = *(const float4*)(ysb0 + min(f0 + 8,  CLAMP));
      D0 = *(const float4*)(ysb0 + min(f0 + 12, CLAMP));
      A1 = *(const float4*)(ysb1 + min(f0,      CLAMP));
      B1 = *(const float4*)(ysb1 + min(f0 + 4,  CLAMP));
      C1 = *(const float4*)(ysb1 + min(f0 + 8,  CLAMP));
      D1 = *(const float4*)(ysb1 + min(f0 + 12, CLAMP));
    }
    const float* __restrict__ xb0 = xbuf0 + (c & 1) * 512;
    const float* __restrict__ xb1 = xbuf1 + (c & 1) * 512;
    const int base = c * 64;
    const int nsteps = min(64, (T_LEN - 1) - base);
    for (int j = 0; j < nsteps; ++j) {
      // y broadcasts (prev step's ds_write; same-wave ordered, fenced)
      const v4f ya0 = *(const v4f*)(cbuf0 + 64);
      const v4f yb0 = *(const v4f*)(cbuf0 + 68);
      const v4f yc0 = *(const v4f*)(cbuf0 + 72);
      const v4f yd0 = *(const v4f*)(cbuf0 + 76);
      const v4f ya1 = *(const v4f*)(cbuf1 + 64);
      const v4f yb1 = *(const v4f*)(cbuf1 + 68);
      const v4f yc1 = *(const v4f*)(cbuf1 + 72);
      const v4f yd1 = *(const v4f*)(cbuf1 + 76);
      // dx reads early: ds_read latency hides under layer-1
      const v2f dx0 = *(const v2f*)(xb0 + j * 8 + d0);
      const v2f dx1 = *(const v2f*)(xb1 + j * 8 + d0);

      // layer-1 full 16-wide dots (8 pk each, two chains each, interleaved)
      const float m_t = fmaf(w1t, t, b1m);  // element-independent
      v2f ma0; ma0.x = m_t;  ma0.y = 0.0f;
      v2f mb0; mb0.x = 0.0f; mb0.y = 0.0f;
      v2f ma1; ma1.x = m_t;  ma1.y = 0.0f;
      v2f mb1; mb1.x = 0.0f; mb1.y = 0.0f;
      pk_fma_v(ma0, W1y2[0], ya0.xy); pk_fma_v(ma1, W1y2[0], ya1.xy);
      pk_fma_v(ma0, W1y2[1], ya0.zw); pk_fma_v(ma1, W1y2[1], ya1.zw);
      pk_fma_v(ma0, W1y2[2], yb0.xy); pk_fma_v(ma1, W1y2[2], yb1.xy);
      pk_fma_v(ma0, W1y2[3], yb0.zw); pk_fma_v(ma1, W1y2[3], yb1.zw);
      pk_fma_v(mb0, W1y2[4], yc0.xy); pk_fma_v(mb1, W1y2[4], yc1.xy);
      pk_fma_v(mb0, W1y2[5], yc0.zw); pk_fma_v(mb1, W1y2[5], yc1.zw);
      pk_fma_v(mb0, W1y2[6], yd0.xy); pk_fma_v(mb1, W1y2[6], yd1.xy);
      pk_fma_v(mb0, W1y2[7], yd0.zw); pk_fma_v(mb1, W1y2[7], yd1.zw);
      const v2f ms0 = ma0 + mb0;
      const v2f ms1 = ma1 + mb1;
      const float m0 = ms0.x + ms0.y;
      const float m1 = ms1.x + ms1.y;

      // silu: u * sigmoid(u), u = -ln2 * m, exp(-u) = exp2(m)
      const float eM0 = fexp2(m0);
      const float eM1 = fexp2(m1);
      const float s0 = (m0 * NLN2f) * frcp(1.0f + eM0);
      const float s1 = (m1 * NLN2f) * frcp(1.0f + eM1);

      // publish s; fenced so broadcast reads can't be hoisted above the writes
      cbuf0[l] = s0;
      cbuf1[l] = s1;
      cfence();
      const v4f g00 = *(const v4f*)(cbuf0 + 16);   // s_g[0..3]   (uniform bcast)
      const v4f g10 = *(const v4f*)(cbuf0 + 20);   // s_g[4..7]
      const v4f g20 = *(const v4f*)(cbuf0 + 24);   // s_g[8..11]
      const v4f g30 = *(const v4f*)(cbuf0 + 28);   // s_g[12..15]
      const v4f sf0 = *(const v4f*)(cbuf0 + q4);   // s_f quartet (4-addr bcast)
      const v4f g01 = *(const v4f*)(cbuf1 + 16);
      const v4f g11 = *(const v4f*)(cbuf1 + 20);
      const v4f g21 = *(const v4f*)(cbuf1 + 24);
      const v4f g31 = *(const v4f*)(cbuf1 + 28);
      const v4f sf1 = *(const v4f*)(cbuf1 + q4);

      // g-dots: 2 rows x 16 per element, two chains each (all-VGPR pk)
      v2f ga0; ga0.x = bg0p; ga0.y = 0.0f;
      v2f gc0; gc0.x = 0.0f; gc0.y = 0.0f;
      v2f gb0; gb0.x = bg1p; gb0.y = 0.0f;
      v2f gd0; gd0.x = 0.0f; gd0.y = 0.0f;
      v2f ga1; ga1.x = bg0p; ga1.y = 0.0f;
      v2f gc1; gc1.x = 0.0f; gc1.y = 0.0f;
      v2f gb1; gb1.x = bg1p; gb1.y = 0.0f;
      v2f gd1; gd1.x = 0.0f; gd1.y = 0.0f;
      pk_fma_v(ga0, G0p[0], g00.xy); pk_fma_v(ga1, G0p[0], g01.xy);
      pk_fma_v(ga0, G0p[1], g00.zw); pk_fma_v(ga1, G0p[1], g01.zw);
      pk_fma_v(ga0, G0p[2], g10.xy); pk_fma_v(ga1, G0p[2], g11.xy);
      pk_fma_v(ga0, G0p[3], g10.zw); pk_fma_v(ga1, G0p[3], g11.zw);
      pk_fma_v(gc0, G0p[4], g20.xy); pk_fma_v(gc1, G0p[4], g21.xy);
      pk_fma_v(gc0, G0p[5], g20.zw); pk_fma_v(gc1, G0p[5], g21.zw);
      pk_fma_v(gc0, G0p[6], g30.xy); pk_fma_v(gc1, G0p[6], g31.xy);
      pk_fma_v(gc0, G0p[7], g30.zw); pk_fma_v(gc1, G0p[7], g31.zw);
      pk_fma_v(gb0, G1p[0], g00.xy); pk_fma_v(gb1, G1p[0], g01.xy);
      pk_fma_v(gb0, G1p[1], g00.zw); pk_fma_v(gb1, G1p[1], g01.zw);
      pk_fma_v(gb0, G1p[2], g10.xy); pk_fma_v(gb1, G1p[2], g11.xy);
      pk_fma_v(gb0, G1p[3], g10.zw); pk_fma_v(gb1, G1p[3], g11.zw);
      pk_fma_v(gd0, G1p[4], g20.xy); pk_fma_v(gd1, G1p[4], g21.xy);
      pk_fma_v(gd0, G1p[5], g20.zw); pk_fma_v(gd1, G1p[5], g21.zw);
      pk_fma_v(gd0, G1p[6], g30.xy); pk_fma_v(gd1, G1p[6], g31.xy);
      pk_fma_v(gd0, G1p[7], g30.zw); pk_fma_v(gd1, G1p[7], g31.zw);

      // f quarter-dots + quad butterfly BEFORE tanh (bias once, post-reduce)
      v2f fa0; fa0.x = 0.0f; fa0.y = 0.0f;
      v2f fa1; fa1.x = 0.0f; fa1.y = 0.0f;
      pk_fma_v(fa0, W2q[0], sf0.xy); pk_fma_v(fa1, W2q[0], sf1.xy);
      pk_fma_v(fa0, W2q[1], sf0.zw); pk_fma_v(fa1, W2q[1], sf1.zw);
      float fp0 = fa0.x + fa0.y;
      float fp1 = fa1.x + fa1.y;
      fp0 = dpp_add<0xB1>(fp0); fp1 = dpp_add<0xB1>(fp1);
      fp0 = dpp_add<0x4E>(fp0); fp1 = dpp_add<0x4E>(fp1);
      const float farg0 = fp0 + b2p;
      const float farg1 = fp1 + b2p;

      // tanh(x) = 1 - 2/(1+exp2(x')) with x' pre-scaled by 2*log2e
      const v2f gs00 = ga0 + gc0;
      const v2f gs10 = gb0 + gd0;
      const v2f gs01 = ga1 + gc1;
      const v2f gs11 = gb1 + gd1;
      const float g0v0 = fmaf(-2.0f, frcp(1.0f + fexp2(gs00.x + gs00.y)), 1.0f);
      const float g1v0 = fmaf(-2.0f, frcp(1.0f + fexp2(gs10.x + gs10.y)), 1.0f);
      const float g0v1 = fmaf(-2.0f, frcp(1.0f + fexp2(gs01.x + gs01.y)), 1.0f);
      const float g1v1 = fmaf(-2.0f, frcp(1.0f + fexp2(gs11.x + gs11.y)), 1.0f);
      const float fv0 = fmaf(-2.0f, frcp(1.0f + fexp2(farg0)), 1.0f);
      const float fv1 = fmaf(-2.0f, frcp(1.0f + fexp2(farg1)), 1.0f);

      // einsum partials + quad butterfly reduce over d
      float pr0 = fmaf(g0v0, dx0.x, g1v0 * dx0.y);
      float pr1 = fmaf(g0v1, dx1.x, g1v1 * dx1.y);
      pr0 = dpp_add<0xB1>(pr0); pr1 = dpp_add<0xB1>(pr1);
      pr0 = dpp_add<0x4E>(pr0); pr1 = dpp_add<0x4E>(pr1);

      y_own0 = y_own0 + (fv0 + pr0);
      y_own1 = y_own1 + (fv1 + pr1);
      cbuf0[ywslot] = y_own0;   // publish y for next step (dump lanes -> 80+l)
      cbuf1[ywslot] = y_own1;
      cfence();
      t += 1.0f;
    }
    // write prefetched chunks into the other buffers (vmcnt drain is off the
    // step critical path: 64 steps of compute covered the load latency)
    float* xbn0 = xbuf0 + ((c + 1) & 1) * 512;
    float* xbn1 = xbuf1 + ((c + 1) & 1) * 512;
    float4 e0, e1;
    e0.x = C0.x - A0.x; e0.y = C0.y - A0.y; e0.z = C0.z - A0.z; e0.w = C0.w - A0.w;
    e1.x = D0.x - B0.x; e1.y = D0.y - B0.y; e1.z = D0.z - B0.z; e1.w = D0.w - B0.w;
    *(float4*)(xbn0 + l * 8)     = e0;
    *(float4*)(xbn0 + l * 8 + 4) = e1;
    e0.x = C1.x - A1.x; e0.y = C1.y - A1.y; e0.z = C1.z - A1.z; e0.w = C1.w - A1.w;
    e1.x = D1.x - B1.x; e1.y = D1.y - B1.y; e1.z = D1.z - B1.z; e1.w = D1.w - B1.w;
    *(float4*)(xbn1 + l * 8)     = e0;
    *(float4*)(xbn1 + l * 8 + 4) = e1;
    cfence();
  }

  // ---- readout at t1 (final y is in cbuf[64..79]) ----
  {
    const float rb0 = rb[0];
    const float o0 = readout_lds(cbuf0, rW, rb0);
    const float o1 = readout_lds(cbuf1, rW, rb0);
    if (l == 0) {
      out[2 * b0 + 1] = o0;
      out[2 * b0 + 3] = o1;
    }
  }
}

extern "C" void kernel_launch(void* const* d_in, const int* in_sizes, int n_in,
                              void* d_out, int out_size, void* d_ws, size_t ws_size,
                              hipStream_t stream) {
  (void)in_sizes; (void)n_in; (void)out_size; (void)d_ws; (void)ws_size;
  const float* ts  = (const float*)d_in[0];
  const float* ys  = (const float*)d_in[1];
  const float* iW1 = (const float*)d_in[2];
  const float* ib1 = (const float*)d_in[3];
  const float* iW2 = (const float*)d_in[4];
  const float* ib2 = (const float*)d_in[5];
  const float* vW1 = (const float*)d_in[6];
  const float* vb1 = (const float*)d_in[7];
  const float* vW2 = (const float*)d_in[8];
  const float* vb2 = (const float*)d_in[9];
  const float* cW1 = (const float*)d_in[10];
  const float* cb1 = (const float*)d_in[11];
  const float* cW2 = (const float*)d_in[12];
  const float* cb2 = (const float*)d_in[13];
  const float* rW  = (const float*)d_in[14];
  const float* rb  = (const float*)d_in[15];
  float* out = (float*)d_out;
  hipLaunchKernelGGL(disc_kernel, dim3(256), dim3(64), 0, stream,
                     ts, ys, iW1, ib1, iW2, ib2, vW1, vb1, vW2, vb2,
                     cW1, cb1, cW2, cb2, rW, rb, out);
}

// Round 5
// 1287.732 us; speedup vs baseline: 1.5058x; 1.5058x over previous
//
#include <hip/hip_runtime.h>

#define T_LEN 4096

typedef float v2f __attribute__((ext_vector_type(2)));
typedef float v4f __attribute__((ext_vector_type(4)));

__device__ __forceinline__ float frcp(float x) { return __builtin_amdgcn_rcpf(x); }
__device__ __forceinline__ float fexp2(float x) { return __builtin_amdgcn_exp2f(x); }

// packed dual-FMA: acc = w*s + acc (VOP3P, full-rate fp32 pairs, all-VGPR).
__device__ __forceinline__ void pk_fma_v(v2f& acc, v2f w, v2f s) {
  asm("v_pk_fma_f32 %0, %1, %2, %0" : "+v"(acc) : "v"(w), "v"(s));
}

// quad_perm DPP butterfly add: xor1 = 0xB1, xor2 = 0x4E
template <int CTRL>
__device__ __forceinline__ float dpp_add(float x) {
  int t = __builtin_amdgcn_mov_dpp(__float_as_int(x), CTRL, 0xF, 0xF, true);
  return x + __int_as_float(t);
}
template <int CTRL>
__device__ __forceinline__ float dpp_movf(float x) {
  return __int_as_float(
      __builtin_amdgcn_mov_dpp(__float_as_int(x), CTRL, 0xF, 0xF, true));
}
template <int CTRL>
__device__ __forceinline__ v2f dpp_mov2(v2f x) {
  v2f r; r.x = dpp_movf<CTRL>(x.x); r.y = dpp_movf<CTRL>(x.y); return r;
}

// register cross-lane gather: returns v from lane (idx/4). No LDS round trip.
__device__ __forceinline__ float bperm(int idx, float v) {
  return __int_as_float(__builtin_amdgcn_ds_bpermute(idx, __float_as_int(v)));
}

// compile-time fence (used only in cold paths / chunk staging)
__device__ __forceinline__ void cfence() { asm volatile("" ::: "memory"); }

#define NLN2f (-0.6931471805599453f)

// readout: y[0..15] lives in cb[64..79]; all lanes compute (uniform), lane 0 stores.
__device__ __forceinline__ float readout_lds(const float* cb,
                                             const float* __restrict__ rW,
                                             float rb0) {
  v4f a = *(const v4f*)(cb + 64);
  v4f b = *(const v4f*)(cb + 68);
  v4f c = *(const v4f*)(cb + 72);
  v4f d = *(const v4f*)(cb + 76);
  float o = rb0;
  o = fmaf(rW[0],  a.x, o); o = fmaf(rW[1],  a.y, o);
  o = fmaf(rW[2],  a.z, o); o = fmaf(rW[3],  a.w, o);
  o = fmaf(rW[4],  b.x, o); o = fmaf(rW[5],  b.y, o);
  o = fmaf(rW[6],  b.z, o); o = fmaf(rW[7],  b.w, o);
  o = fmaf(rW[8],  c.x, o); o = fmaf(rW[9],  c.y, o);
  o = fmaf(rW[10], c.z, o); o = fmaf(rW[11], c.w, o);
  o = fmaf(rW[12], d.x, o); o = fmaf(rW[13], d.y, o);
  o = fmaf(rW[14], d.z, o); o = fmaf(rW[15], d.w, o);
  return o;
}

// One wave (64 lanes) per batch element; block = 1 wave => no barriers.
// NO LDS round trips in the hot loop: all cross-lane movement is ds_bpermute
// (register gather) + quad DPP. Lane l = 16a+4b+c; quad q=l>>2 owns hidden
// row h=q. y[q] is quad-replicated in y_own (butterflies keep it bitwise
// uniform). Per step:
//   y-gather  : 4 bpermutes -> yg[j]=y[4c+j]; quad-cooperative layer-1 dot
//               (lane covers cols 4c..4c+3 of rows (p=0,q),(p=1,q)), quad
//               butterfly completes both dots; t/bias term only on c==0.
//   silu      : s0v=s[0][q], s1v=s[1][q] (quad-uniform).
//   s-gather  : 8 bpermutes -> sg0[j]=s[0][4c+j], sg1[j]=s[1][4c+j].
//   g partial : lane computes col-quartet partials for all 8 rows (q,d);
//               directed 2-stage quad reduce (cndmask + quad_perm) lands
//               rows (2l,2l+1) in a fixed v2f -> biases/tanh/einsum/update
//               identical to the verified R3 code.
//   f partial : col-quartet of row q + full quad butterfly (all lanes get fv).
// exp2 folding unchanged: W1 by -log2e, W2/G by 2*log2e*0.909, biases TSB.
__global__ __launch_bounds__(64) void disc_kernel(
    const float* __restrict__ ts, const float* __restrict__ ys,
    const float* __restrict__ iW1, const float* __restrict__ ib1,
    const float* __restrict__ iW2, const float* __restrict__ ib2,
    const float* __restrict__ vW1, const float* __restrict__ vb1,
    const float* __restrict__ vW2, const float* __restrict__ vb2,
    const float* __restrict__ cW1, const float* __restrict__ cb1,
    const float* __restrict__ cW2, const float* __restrict__ cb2,
    const float* __restrict__ rW, const float* __restrict__ rb,
    float* __restrict__ out)
{
  const int b   = blockIdx.x;
  const int l   = threadIdx.x;
  const int h16 = l & 15;
  const int a   = (l >> 4) & 3;
  const int c   = l & 3;
  const int q   = l >> 2;          // quad id == hidden row h
  const int d0  = 2 * c;           // einsum d-pair base (== (2*l)&7)
  const int ywslot = (c == 0) ? (64 + q) : (80 + l);  // y publish / dump

  __shared__ __align__(16) float sbuf[16];    // init relu staging
  __shared__ __align__(16) float cbuf[160];   // [64..79] y for init/readout
  __shared__ __align__(16) float xbuf[1024];  // 2 x 64 dx-rows (8 floats each)

  const float* __restrict__ ysb = ys + (size_t)b * (T_LEN * 8);

  const float NL2E = -1.4426950408889634f;                 // -log2(e)
  const float TSW  = 2.0f * 1.4426950408889634f * 0.909f;  // weight scale (tanh arg)
  const float TSB  = 2.0f * 1.4426950408889634f;           // bias scale (tanh arg)

  // ---- bpermute gather indices: source lane 16c+4j+a holds value[4c+j] ----
  int idx0 = 4 * (16 * c + 0  + a);
  int idx1 = 4 * (16 * c + 4  + a);
  int idx2 = 4 * (16 * c + 8  + a);
  int idx3 = 4 * (16 * c + 12 + a);

  // ---- per-lane weights (scaled) ----
  // layer-1: rows (p=0: vW1[q]), (p=1: cW1[q]), cols 1+4c+j
  float W1v4[4], W1c4[4];
#pragma unroll
  for (int j = 0; j < 4; ++j) {
    W1v4[j] = NL2E * vW1[q * 17 + 1 + 4 * c + j];
    W1c4[j] = NL2E * cW1[q * 17 + 1 + 4 * c + j];
  }
  const float w1t0 = (c == 0) ? NL2E * vW1[q * 17] : 0.0f;
  const float b1m0 = (c == 0) ? NL2E * vb1[q]      : 0.0f;
  const float w1t1 = (c == 0) ? NL2E * cW1[q * 17] : 0.0f;
  const float b1m1 = (c == 0) ? NL2E * cb1[q]      : 0.0f;
  // f: row q of vW2, cols 4c+j
  float W2f4[4];
#pragma unroll
  for (int j = 0; j < 4; ++j) W2f4[j] = TSW * vW2[q * 16 + 4 * c + j];
  // g: rows 8q+d (d=0..7), cols 4c+j, packed by d-pairs: Gp[e][j] = (row 2e, row 2e+1)
  v2f Gp[4][4];
#pragma unroll
  for (int e = 0; e < 4; ++e) {
#pragma unroll
    for (int j = 0; j < 4; ++j) {
      v2f w;
      w.x = TSW * cW2[(8 * q + 2 * e)     * 16 + 4 * c + j];
      w.y = TSW * cW2[(8 * q + 2 * e + 1) * 16 + 4 * c + j];
      Gp[e][j] = w;
    }
  }
  const float b2p  = TSB * vb2[q];
  const float bg0p = TSB * cb2[2 * l];      // row 8q+2c   == 2l
  const float bg1p = TSB * cb2[2 * l + 1];  // row 8q+2c+1 == 2l+1

  const float t0 = ts[0];

  // ---- initial hidden state (cold path, via LDS; same-wave DS is ordered) ----
  float y_own;
  {
    float acc = ib1[h16] + iW1[h16 * 9] * t0;
#pragma unroll
    for (int d = 0; d < 8; ++d) acc = fmaf(iW1[h16 * 9 + 1 + d], ysb[d], acc);
    sbuf[h16] = fmaxf(acc, 0.0f);
    cfence();
    float acc2 = ib2[h16];
#pragma unroll
    for (int k = 0; k < 16; ++k) acc2 = fmaf(iW2[h16 * 16 + k], sbuf[k], acc2);
    cbuf[64 + h16] = acc2;     // duplicate same-addr same-value writes (init only)
    cfence();
    y_own = cbuf[64 + q];      // quad-replicated y[q]
  }

  // ---- readout at t0 ----
  {
    const float o = readout_lds(cbuf, rW, rb[0]);
    if (l == 0) out[2 * b] = o;
  }

  // ---- dx staging: 64-row chunks, double-buffered, prefetch next chunk ----
  const int CLAMP = T_LEN * 8 - 4;
  float4 A, Bq, Cq, Dq;
  {
    const int f0 = l * 8;
    A  = *(const float4*)(ysb + min(f0,      CLAMP));
    Bq = *(const float4*)(ysb + min(f0 + 4,  CLAMP));
    Cq = *(const float4*)(ysb + min(f0 + 8,  CLAMP));
    Dq = *(const float4*)(ysb + min(f0 + 12, CLAMP));
    float4 e0, e1;
    e0.x = Cq.x - A.x;  e0.y = Cq.y - A.y;  e0.z = Cq.z - A.z;  e0.w = Cq.w - A.w;
    e1.x = Dq.x - Bq.x; e1.y = Dq.y - Bq.y; e1.z = Dq.z - Bq.z; e1.w = Dq.w - Bq.w;
    *(float4*)(xbuf + l * 8)     = e0;
    *(float4*)(xbuf + l * 8 + 4) = e1;
    cfence();
  }

  float t = t0;
  for (int ch = 0; ch < 64; ++ch) {
    // prefetch chunk ch+1 (clamped; last chunk re-reads itself, harmless)
    {
      const int cn = min(ch + 1, 63);
      const int f0 = cn * 512 + l * 8;
      A  = *(const float4*)(ysb + min(f0,      CLAMP));
      Bq = *(const float4*)(ysb + min(f0 + 4,  CLAMP));
      Cq = *(const float4*)(ysb + min(f0 + 8,  CLAMP));
      Dq = *(const float4*)(ysb + min(f0 + 12, CLAMP));
    }
    const float* __restrict__ xb = xbuf + (ch & 1) * 512;
    const int base = ch * 64;
    const int nsteps = min(64, (T_LEN - 1) - base);
    for (int j = 0; j < nsteps; ++j) {
      // dx read early: ds_read latency hides under y-gather/layer-1
      const v2f dx = *(const v2f*)(xb + j * 8 + d0);

      // ---- y-gather: yg[j] = y[4c+j] (register gather, no round trip) ----
      const float yg0 = bperm(idx0, y_own);
      const float yg1 = bperm(idx1, y_own);
      const float yg2 = bperm(idx2, y_own);
      const float yg3 = bperm(idx3, y_own);

      // ---- layer-1 quad-cooperative partials (both groups) ----
      float acc0 = fmaf(w1t0, t, b1m0);
      float acc1 = fmaf(w1t1, t, b1m1);
      acc0 = fmaf(W1v4[0], yg0, acc0);
      acc0 = fmaf(W1v4[1], yg1, acc0);
      acc0 = fmaf(W1v4[2], yg2, acc0);
      acc0 = fmaf(W1v4[3], yg3, acc0);
      acc1 = fmaf(W1c4[0], yg0, acc1);
      acc1 = fmaf(W1c4[1], yg1, acc1);
      acc1 = fmaf(W1c4[2], yg2, acc1);
      acc1 = fmaf(W1c4[3], yg3, acc1);
      // quad butterfly -> m[p][q] replicated across quad (bitwise uniform)
      acc0 = dpp_add<0xB1>(acc0); acc0 = dpp_add<0x4E>(acc0);
      acc1 = dpp_add<0xB1>(acc1); acc1 = dpp_add<0x4E>(acc1);

      // ---- silu: u*sigmoid(u), u = -ln2*m, exp(-u) = exp2(m) ----
      const float eM0 = fexp2(acc0);
      const float s0v = (acc0 * NLN2f) * frcp(1.0f + eM0);
      const float eM1 = fexp2(acc1);
      const float s1v = (acc1 * NLN2f) * frcp(1.0f + eM1);

      // ---- s-gather: sg0[j]=s[0][4c+j], sg1[j]=s[1][4c+j] ----
      const float sg00 = bperm(idx0, s0v);
      const float sg01 = bperm(idx1, s0v);
      const float sg02 = bperm(idx2, s0v);
      const float sg03 = bperm(idx3, s0v);
      const float sg10 = bperm(idx0, s1v);
      const float sg11 = bperm(idx1, s1v);
      const float sg12 = bperm(idx2, s1v);
      const float sg13 = bperm(idx3, s1v);

      // ---- g partials: 8 rows (q,d), this lane's col-quartet ----
      v2f sd0; sd0.x = sg10; sd0.y = sg10;
      v2f sd1; sd1.x = sg11; sd1.y = sg11;
      v2f sd2; sd2.x = sg12; sd2.y = sg12;
      v2f sd3; sd3.x = sg13; sd3.y = sg13;
      v2f P0; P0.x = 0.0f; P0.y = 0.0f;
      v2f P1; P1.x = 0.0f; P1.y = 0.0f;
      v2f P2; P2.x = 0.0f; P2.y = 0.0f;
      v2f P3; P3.x = 0.0f; P3.y = 0.0f;
      pk_fma_v(P0, Gp[0][0], sd0); pk_fma_v(P0, Gp[0][1], sd1);
      pk_fma_v(P0, Gp[0][2], sd2); pk_fma_v(P0, Gp[0][3], sd3);
      pk_fma_v(P1, Gp[1][0], sd0); pk_fma_v(P1, Gp[1][1], sd1);
      pk_fma_v(P1, Gp[1][2], sd2); pk_fma_v(P1, Gp[1][3], sd3);
      pk_fma_v(P2, Gp[2][0], sd0); pk_fma_v(P2, Gp[2][1], sd1);
      pk_fma_v(P2, Gp[2][2], sd2); pk_fma_v(P2, Gp[2][3], sd3);
      pk_fma_v(P3, Gp[3][0], sd0); pk_fma_v(P3, Gp[3][1], sd1);
      pk_fma_v(P3, Gp[3][2], sd2); pk_fma_v(P3, Gp[3][3], sd3);

      // ---- f partial: row q col-quartet + full quad butterfly ----
      float fp = W2f4[0] * sg00;
      fp = fmaf(W2f4[1], sg01, fp);
      fp = fmaf(W2f4[2], sg02, fp);
      fp = fmaf(W2f4[3], sg03, fp);
      fp = dpp_add<0xB1>(fp); fp = dpp_add<0x4E>(fp);
      const float farg = fp + b2p;

      // ---- directed quad reduce: land rows (2l, 2l+1) in fixed v2f G ----
      const bool s2b = (c & 2) != 0;
      const bool s1b = (c & 1) != 0;
      // stage 1: partner c^2 (0x4E); low-c keeps d0..3, high-c keeps d4..7
      v2f K0 = s2b ? P2 : P0;  v2f X0 = s2b ? P0 : P2;
      v2f K1 = s2b ? P3 : P1;  v2f X1 = s2b ? P1 : P3;
      v2f R0 = dpp_mov2<0x4E>(X0);
      v2f R1 = dpp_mov2<0x4E>(X1);
      v2f Q0 = K0 + R0;
      v2f Q1 = K1 + R1;
      // stage 2: partner c^1 (0xB1); even-c keeps first pair, odd-c second
      v2f K = s1b ? Q1 : Q0;  v2f X = s1b ? Q0 : Q1;
      v2f R = dpp_mov2<0xB1>(X);
      const v2f G = K + R;   // (gsum[2c], gsum[2c+1]) summed over the quad

      // ---- tanh(x) = 1 - 2/(1+exp2(x')), x' pre-scaled by 2*log2e ----
      const float g0v = fmaf(-2.0f, frcp(1.0f + fexp2(G.x + bg0p)), 1.0f);
      const float g1v = fmaf(-2.0f, frcp(1.0f + fexp2(G.y + bg1p)), 1.0f);
      const float fv  = fmaf(-2.0f, frcp(1.0f + fexp2(farg)), 1.0f);

      // ---- einsum partial + quad butterfly reduce over d ----
      float pr = fmaf(g0v, dx.x, g1v * dx.y);
      pr = dpp_add<0xB1>(pr);
      pr = dpp_add<0x4E>(pr);

      y_own = y_own + (fv + pr);   // stays quad-uniform (bitwise)
      t += 1.0f;
    }
    // write prefetched chunk into the other buffer (vmcnt drain is off the
    // step critical path: 64 steps of compute covered the load latency)
    float* xbn = xbuf + ((ch + 1) & 1) * 512;
    float4 e0, e1;
    e0.x = Cq.x - A.x;  e0.y = Cq.y - A.y;  e0.z = Cq.z - A.z;  e0.w = Cq.w - A.w;
    e1.x = Dq.x - Bq.x; e1.y = Dq.y - Bq.y; e1.z = Dq.z - Bq.z; e1.w = Dq.w - Bq.w;
    *(float4*)(xbn + l * 8)     = e0;
    *(float4*)(xbn + l * 8 + 4) = e1;
    cfence();
  }

  // ---- publish final y once, then readout at t1 ----
  cbuf[ywslot] = y_own;     // c==0 lanes -> real slots, rest -> dump region
  cfence();
  {
    const float o = readout_lds(cbuf, rW, rb[0]);
    if (l == 0) out[2 * b + 1] = o;
  }
}

extern "C" void kernel_launch(void* const* d_in, const int* in_sizes, int n_in,
                              void* d_out, int out_size, void* d_ws, size_t ws_size,
                              hipStream_t stream) {
  (void)in_sizes; (void)n_in; (void)out_size; (void)d_ws; (void)ws_size;
  const float* ts  = (const float*)d_in[0];
  const float* ys  = (const float*)d_in[1];
  const float* iW1 = (const float*)d_in[2];
  const float* ib1 = (const float*)d_in[3];
  const float* iW2 = (const float*)d_in[4];
  const float* ib2 = (const float*)d_in[5];
  const float* vW1 = (const float*)d_in[6];
  const float* vb1 = (const float*)d_in[7];
  const float* vW2 = (const float*)d_in[8];
  const float* vb2 = (const float*)d_in[9];
  const float* cW1 = (const float*)d_in[10];
  const float* cb1 = (const float*)d_in[11];
  const float* cW2 = (const float*)d_in[12];
  const float* cb2 = (const float*)d_in[13];
  const float* rW  = (const float*)d_in[14];
  const float* rb  = (const float*)d_in[15];
  float* out = (float*)d_out;
  hipLaunchKernelGGL(disc_kernel, dim3(512), dim3(64), 0, stream,
                     ts, ys, iW1, ib1, iW2, ib2, vW1, vb1, vW2, vb2,
                     cW1, cb1, cW2, cb2, rW, rb, out);
}

// Round 6
// 1112.852 us; speedup vs baseline: 1.7424x; 1.1571x over previous
//
#include <hip/hip_runtime.h>

#define T_LEN 4096

typedef float v2f __attribute__((ext_vector_type(2)));
typedef float v4f __attribute__((ext_vector_type(4)));

__device__ __forceinline__ float frcp(float x) { return __builtin_amdgcn_rcpf(x); }
__device__ __forceinline__ float fexp2(float x) { return __builtin_amdgcn_exp2f(x); }

// packed dual-FMA: acc = w*s + acc (VOP3P, full-rate fp32 pairs, all-VGPR).
__device__ __forceinline__ void pk_fma_v(v2f& acc, v2f w, v2f s) {
  asm("v_pk_fma_f32 %0, %1, %2, %0" : "+v"(acc) : "v"(w), "v"(s));
}

// quad_perm DPP butterfly adds: xor1 = 0xB1, xor2 = 0x4E
template <int CTRL>
__device__ __forceinline__ float dpp_add(float x) {
  int t = __builtin_amdgcn_mov_dpp(__float_as_int(x), CTRL, 0xF, 0xF, true);
  return x + __int_as_float(t);
}

// cross-half sum: every lane gets (low-half mate's x) + (high-half mate's x).
// Robust form: explicit two distinct registers (early-clobber copy) so the
// swap can never be register-aliased into a no-op; a+b is correct under
// either orientation of the swap semantics.
__device__ __forceinline__ float half_sum(float x) {
  float a = x, b;
  asm("v_mov_b32 %1, %0\n\t"
      "v_permlane32_swap_b32 %0, %1"
      : "+v"(a), "=&v"(b));
  return a + b;
}

// compile-time fence: forbids reordering LDS publish vs dependent broadcast
// reads (float stores vs v4f reinterpret loads could be TBAA-noalias).
__device__ __forceinline__ void cfence() { asm volatile("" ::: "memory"); }

#define NLN2f (-0.6931471805599453f)

// readout: y[0..15] lives in cb[64..79]; all lanes compute (uniform), lane 0 stores.
__device__ __forceinline__ float readout_lds(const float* cb,
                                             const float* __restrict__ rW,
                                             float rb0) {
  v4f a = *(const v4f*)(cb + 64);
  v4f b = *(const v4f*)(cb + 68);
  v4f c = *(const v4f*)(cb + 72);
  v4f d = *(const v4f*)(cb + 76);
  float o = rb0;
  o = fmaf(rW[0],  a.x, o); o = fmaf(rW[1],  a.y, o);
  o = fmaf(rW[2],  a.z, o); o = fmaf(rW[3],  a.w, o);
  o = fmaf(rW[4],  b.x, o); o = fmaf(rW[5],  b.y, o);
  o = fmaf(rW[6],  b.z, o); o = fmaf(rW[7],  b.w, o);
  o = fmaf(rW[8],  c.x, o); o = fmaf(rW[9],  c.y, o);
  o = fmaf(rW[10], c.z, o); o = fmaf(rW[11], c.w, o);
  o = fmaf(rW[12], d.x, o); o = fmaf(rW[13], d.y, o);
  o = fmaf(rW[14], d.z, o); o = fmaf(rW[15], d.w, o);
  return o;
}

// One wave (64 lanes) per batch element; block = 1 wave => no barriers.
// vs the verified R3 kernel:
//  - layer-1 is half-split: lanes 0..31 dot y[0..7], lanes 32..63 dot
//    y[8..15] (same (p,h16) rows), merged via robust v_permlane32_swap.
//    t/bias term only in the low half.
//  - the y-broadcast reads and the dx read for step n+1 are issued at the
//    END of step n (right after the y ds_write + fence) and carried in
//    registers, so their DS latency hides under the loop-back + layer-1
//    issue instead of stalling the top of the step.
// Everything else (silu, s round trip, g/f dots, tanh, einsum, reduces)
// is verbatim the verified R3 code.
__global__ __launch_bounds__(64) void disc_kernel(
    const float* __restrict__ ts, const float* __restrict__ ys,
    const float* __restrict__ iW1, const float* __restrict__ ib1,
    const float* __restrict__ iW2, const float* __restrict__ ib2,
    const float* __restrict__ vW1, const float* __restrict__ vb1,
    const float* __restrict__ vW2, const float* __restrict__ vb2,
    const float* __restrict__ cW1, const float* __restrict__ cb1,
    const float* __restrict__ cW2, const float* __restrict__ cb2,
    const float* __restrict__ rW, const float* __restrict__ rb,
    float* __restrict__ out)
{
  const int b    = blockIdx.x;
  const int l    = threadIdx.x;
  const int h16  = l & 15;
  const int p    = (l >> 4) & 1;
  const int hf   = l >> 2;
  const int d0   = (2 * l) & 7;
  const int q4   = 4 * (l & 3);        // f-quartet base (s_f columns)
  const int hoff = (l >> 5) * 8;       // y-half offset (0 or 8)
  const int ywslot = ((l & 3) == 0) ? (64 + hf) : (80 + l);  // y write / dump

  __shared__ __align__(16) float sbuf[16];    // init relu staging
  __shared__ __align__(16) float cbuf[160];   // [0..63] s, [64..79] y, [80..143] dump
  __shared__ __align__(16) float xbuf[1040];  // 2 x 64 dx-rows (8 floats) + pad

  const float* __restrict__ ysb = ys + (size_t)b * (T_LEN * 8);

  const float NL2E = -1.4426950408889634f;                 // -log2(e)
  const float TSW  = 2.0f * 1.4426950408889634f * 0.909f;  // weight scale (tanh arg)
  const float TSB  = 2.0f * 1.4426950408889634f;           // bias scale (tanh arg)

  // ---- per-lane weights (scaled) ----
  float w1t, b1m;
  v2f W1y2[4];
  {
    const float* W1 = p ? cW1 : vW1;
    const float* bv = p ? cb1 : vb1;
    w1t = NL2E * W1[h16 * 17];
    b1m = NL2E * bv[h16];
    const int cbase = 1 + hoff;  // y-col base: 1 (low half) or 9 (high half)
#pragma unroll
    for (int k = 0; k < 4; ++k) {
      v2f w; w.x = NL2E * W1[h16 * 17 + cbase + 2 * k];
             w.y = NL2E * W1[h16 * 17 + cbase + 2 * k + 1];
      W1y2[k] = w;
    }
    if (l >= 32) { w1t = 0.0f; b1m = 0.0f; }  // t/bias counted once (low half)
  }
  v2f W2q[2];
#pragma unroll
  for (int j = 0; j < 2; ++j) {
    v2f w; w.x = TSW * vW2[hf * 16 + q4 + 2 * j];
           w.y = TSW * vW2[hf * 16 + q4 + 2 * j + 1];
    W2q[j] = w;
  }
  v2f G0p[8], G1p[8];
#pragma unroll
  for (int k = 0; k < 8; ++k) {
    v2f c0; c0.x = TSW * cW2[(2 * l) * 16 + 2 * k]; c0.y = TSW * cW2[(2 * l) * 16 + 2 * k + 1];
    G0p[k] = c0;
    v2f c1; c1.x = TSW * cW2[(2 * l + 1) * 16 + 2 * k]; c1.y = TSW * cW2[(2 * l + 1) * 16 + 2 * k + 1];
    G1p[k] = c1;
  }
  const float b2p  = TSB * vb2[hf];
  const float bg0p = TSB * cb2[2 * l];
  const float bg1p = TSB * cb2[2 * l + 1];

  const float t0 = ts[0];

  // ---- initial hidden state (cold path, via LDS; same-wave DS is ordered) ----
  float y_own;
  {
    float acc = ib1[h16] + iW1[h16 * 9] * t0;
#pragma unroll
    for (int d = 0; d < 8; ++d) acc = fmaf(iW1[h16 * 9 + 1 + d], ysb[d], acc);
    sbuf[h16] = fmaxf(acc, 0.0f);
    cfence();
    float acc2 = ib2[h16];
#pragma unroll
    for (int k = 0; k < 16; ++k) acc2 = fmaf(iW2[h16 * 16 + k], sbuf[k], acc2);
    cbuf[64 + h16] = acc2;     // duplicate same-addr same-value writes (init only)
    cfence();
    y_own = cbuf[64 + hf];
  }

  // ---- readout at t0 ----
  {
    const float o = readout_lds(cbuf, rW, rb[0]);
    if (l == 0) out[2 * b] = o;
  }

  // ---- dx staging: 64-row chunks, double-buffered, prefetch next chunk ----
  const int CLAMP = T_LEN * 8 - 4;
  float4 A, Bq, Cq, Dq;
  {
    const int f0 = l * 8;
    A  = *(const float4*)(ysb + min(f0,      CLAMP));
    Bq = *(const float4*)(ysb + min(f0 + 4,  CLAMP));
    Cq = *(const float4*)(ysb + min(f0 + 8,  CLAMP));
    Dq = *(const float4*)(ysb + min(f0 + 12, CLAMP));
    float4 e0, e1;
    e0.x = Cq.x - A.x;  e0.y = Cq.y - A.y;  e0.z = Cq.z - A.z;  e0.w = Cq.w - A.w;
    e1.x = Dq.x - Bq.x; e1.y = Dq.y - Bq.y; e1.z = Dq.z - Bq.z; e1.w = Dq.w - Bq.w;
    *(float4*)(xbuf + l * 8)     = e0;
    *(float4*)(xbuf + l * 8 + 4) = e1;
    cfence();
  }

  // ---- prime pipelined loads (y halves + first dx) ----
  v4f ya = *(const v4f*)(cbuf + 64 + hoff);
  v4f yb = *(const v4f*)(cbuf + 64 + hoff + 4);
  v2f dxc = *(const v2f*)(xbuf + d0);

  float t = t0;
  for (int c = 0; c < 64; ++c) {
    // prefetch chunk c+1 (clamped; last chunk re-reads itself, harmless)
    {
      const int cn = min(c + 1, 63);
      const int f0 = cn * 512 + l * 8;
      A  = *(const float4*)(ysb + min(f0,      CLAMP));
      Bq = *(const float4*)(ysb + min(f0 + 4,  CLAMP));
      Cq = *(const float4*)(ysb + min(f0 + 8,  CLAMP));
      Dq = *(const float4*)(ysb + min(f0 + 12, CLAMP));
    }
    const float* __restrict__ xb = xbuf + (c & 1) * 512;
    const int base = c * 64;
    const int nsteps = min(64, (T_LEN - 1) - base);
    for (int j = 0; j < nsteps; ++j) {
      const v2f dx = dxc;   // pipelined from previous step's bottom

      // layer-1 half-dot (4 pk) on carried y regs, then cross-half merge
      const float m_t = fmaf(w1t, t, b1m);
      v2f acc; acc.x = m_t; acc.y = 0.0f;
      pk_fma_v(acc, W1y2[0], ya.xy);
      pk_fma_v(acc, W1y2[1], ya.zw);
      pk_fma_v(acc, W1y2[2], yb.xy);
      pk_fma_v(acc, W1y2[3], yb.zw);
      const float m = half_sum(acc.x + acc.y);

      // silu: u * sigmoid(u), u = -ln2 * m, exp(-u) = exp2(m)
      const float eM = fexp2(m);
      const float s  = (m * NLN2f) * frcp(1.0f + eM);

      // publish s; fenced so broadcast reads can't be hoisted above the write
      cbuf[l] = s;
      cfence();
      const v4f g0 = *(const v4f*)(cbuf + 16);   // s_g[0..3]   (uniform bcast)
      const v4f g1 = *(const v4f*)(cbuf + 20);   // s_g[4..7]
      const v4f g2 = *(const v4f*)(cbuf + 24);   // s_g[8..11]
      const v4f g3 = *(const v4f*)(cbuf + 28);   // s_g[12..15]
      const v4f sf = *(const v4f*)(cbuf + q4);   // s_f quartet (4-addr bcast)

      // g-dots: 2 rows x 16, two chains each (all-VGPR pk)
      v2f ga; ga.x = bg0p; ga.y = 0.0f;
      v2f gc; gc.x = 0.0f; gc.y = 0.0f;
      v2f gb; gb.x = bg1p; gb.y = 0.0f;
      v2f gd; gd.x = 0.0f; gd.y = 0.0f;
      pk_fma_v(ga, G0p[0], g0.xy); pk_fma_v(ga, G0p[1], g0.zw);
      pk_fma_v(ga, G0p[2], g1.xy); pk_fma_v(ga, G0p[3], g1.zw);
      pk_fma_v(gc, G0p[4], g2.xy); pk_fma_v(gc, G0p[5], g2.zw);
      pk_fma_v(gc, G0p[6], g3.xy); pk_fma_v(gc, G0p[7], g3.zw);
      pk_fma_v(gb, G1p[0], g0.xy); pk_fma_v(gb, G1p[1], g0.zw);
      pk_fma_v(gb, G1p[2], g1.xy); pk_fma_v(gb, G1p[3], g1.zw);
      pk_fma_v(gd, G1p[4], g2.xy); pk_fma_v(gd, G1p[5], g2.zw);
      pk_fma_v(gd, G1p[6], g3.xy); pk_fma_v(gd, G1p[7], g3.zw);

      // f quarter-dot + quad butterfly BEFORE tanh (bias once, post-reduce)
      v2f fa; fa.x = 0.0f; fa.y = 0.0f;
      pk_fma_v(fa, W2q[0], sf.xy);
      pk_fma_v(fa, W2q[1], sf.zw);
      float fp = fa.x + fa.y;
      fp = dpp_add<0xB1>(fp);
      fp = dpp_add<0x4E>(fp);
      const float farg = fp + b2p;

      // tanh(x) = 1 - 2/(1+exp2(x')) with x' pre-scaled by 2*log2e
      const v2f gs0 = ga + gc;
      const v2f gs1 = gb + gd;
      const float g0v = fmaf(-2.0f, frcp(1.0f + fexp2(gs0.x + gs0.y)), 1.0f);
      const float g1v = fmaf(-2.0f, frcp(1.0f + fexp2(gs1.x + gs1.y)), 1.0f);
      const float fv  = fmaf(-2.0f, frcp(1.0f + fexp2(farg)), 1.0f);

      // einsum partial + quad butterfly reduce over d
      float pr = fmaf(g0v, dx.x, g1v * dx.y);
      pr = dpp_add<0xB1>(pr);
      pr = dpp_add<0x4E>(pr);

      y_own = y_own + (fv + pr);
      cbuf[ywslot] = y_own;   // publish y for next step (dump lanes -> 80+l)
      cfence();
      // pipelined loads for the NEXT step: issue right after the publish so
      // their DS latency hides under loop-back + layer-1 issue.
      ya = *(const v4f*)(cbuf + 64 + hoff);
      yb = *(const v4f*)(cbuf + 64 + hoff + 4);
      dxc = *(const v2f*)(xb + (j + 1) * 8 + d0);  // j+1==64 lands in pad/other
                                                   // buffer; corrected below
      t += 1.0f;
    }
    // write prefetched chunk into the other buffer (vmcnt drain is off the
    // step critical path: 64 steps of compute covered the load latency)
    float* xbn = xbuf + ((c + 1) & 1) * 512;
    float4 e0, e1;
    e0.x = Cq.x - A.x;  e0.y = Cq.y - A.y;  e0.z = Cq.z - A.z;  e0.w = Cq.w - A.w;
    e1.x = Dq.x - Bq.x; e1.y = Dq.y - Bq.y; e1.z = Dq.z - Bq.z; e1.w = Dq.w - Bq.w;
    *(float4*)(xbn + l * 8)     = e0;
    *(float4*)(xbn + l * 8 + 4) = e1;
    cfence();
    // correct the pipelined dx for the first step of the next chunk
    dxc = *(const v2f*)(xbn + d0);
  }

  // ---- readout at t1 (final y is in cbuf[64..79]) ----
  {
    const float o = readout_lds(cbuf, rW, rb[0]);
    if (l == 0) out[2 * b + 1] = o;
  }
}

extern "C" void kernel_launch(void* const* d_in, const int* in_sizes, int n_in,
                              void* d_out, int out_size, void* d_ws, size_t ws_size,
                              hipStream_t stream) {
  (void)in_sizes; (void)n_in; (void)out_size; (void)d_ws; (void)ws_size;
  const float* ts  = (const float*)d_in[0];
  const float* ys  = (const float*)d_in[1];
  const float* iW1 = (const float*)d_in[2];
  const float* ib1 = (const float*)d_in[3];
  const float* iW2 = (const float*)d_in[4];
  const float* ib2 = (const float*)d_in[5];
  const float* vW1 = (const float*)d_in[6];
  const float* vb1 = (const float*)d_in[7];
  const float* vW2 = (const float*)d_in[8];
  const float* vb2 = (const float*)d_in[9];
  const float* cW1 = (const float*)d_in[10];
  const float* cb1 = (const float*)d_in[11];
  const float* cW2 = (const float*)d_in[12];
  const float* cb2 = (const float*)d_in[13];
  const float* rW  = (const float*)d_in[14];
  const float* rb  = (const float*)d_in[15];
  float* out = (float*)d_out;
  hipLaunchKernelGGL(disc_kernel, dim3(512), dim3(64), 0, stream,
                     ts, ys, iW1, ib1, iW2, ib2, vW1, vb1, vW2, vb2,
                     cW1, cb1, cW2, cb2, rW, rb, out);
}

// Round 9
// 1105.294 us; speedup vs baseline: 1.7543x; 1.0068x over previous
//
#include <hip/hip_runtime.h>

#define T_LEN 4096

typedef float v2f __attribute__((ext_vector_type(2)));
typedef float v4f __attribute__((ext_vector_type(4)));

__device__ __forceinline__ float frcp(float x) { return __builtin_amdgcn_rcpf(x); }
__device__ __forceinline__ float fexp2(float x) { return __builtin_amdgcn_exp2f(x); }

// packed dual-FMA: acc = w*s + acc (VOP3P, full-rate fp32 pairs, all-VGPR).
__device__ __forceinline__ void pk_fma_v(v2f& acc, v2f w, v2f s) {
  asm("v_pk_fma_f32 %0, %1, %2, %0" : "+v"(acc) : "v"(w), "v"(s));
}

// quad_perm DPP butterfly adds: xor1 = 0xB1, xor2 = 0x4E
template <int CTRL>
__device__ __forceinline__ float dpp_add(float x) {
  int t = __builtin_amdgcn_mov_dpp(__float_as_int(x), CTRL, 0xF, 0xF, true);
  return x + __int_as_float(t);
}
template <int CTRL>
__device__ __forceinline__ float dpp_movf(float x) {
  return __int_as_float(
      __builtin_amdgcn_mov_dpp(__float_as_int(x), CTRL, 0xF, 0xF, true));
}

// register cross-lane gather (verified in R5): returns v from lane (idx/4).
__device__ __forceinline__ float bperm(int idx, float v) {
  return __int_as_float(__builtin_amdgcn_ds_bpermute(idx, __float_as_int(v)));
}

// cross-half (lanes l <-> l^32) sum via permlane32_swap; orientation-immune
// because the result is a+b. Proven in R6.
__device__ __forceinline__ float half_sum(float x) {
  float a = x, b;
  asm("v_mov_b32 %1, %0\n\t"
      "v_permlane32_swap_b32 %0, %1"
      : "+v"(a), "=&v"(b));
  return a + b;
}

// compile-time fence: forbids reordering LDS publish vs dependent broadcast
// reads (float stores vs v4f reinterpret loads could be TBAA-noalias).
__device__ __forceinline__ void cfence() { asm volatile("" ::: "memory"); }

#define NLN2f (-0.6931471805599453f)

// readout: y[0..15] lives in cb[64..79]; all lanes compute (uniform), lane 0 stores.
__device__ __forceinline__ float readout_lds(const float* cb,
                                             const float* __restrict__ rW,
                                             float rb0) {
  v4f a = *(const v4f*)(cb + 64);
  v4f b = *(const v4f*)(cb + 68);
  v4f c = *(const v4f*)(cb + 72);
  v4f d = *(const v4f*)(cb + 76);
  float o = rb0;
  o = fmaf(rW[0],  a.x, o); o = fmaf(rW[1],  a.y, o);
  o = fmaf(rW[2],  a.z, o); o = fmaf(rW[3],  a.w, o);
  o = fmaf(rW[4],  b.x, o); o = fmaf(rW[5],  b.y, o);
  o = fmaf(rW[6],  b.z, o); o = fmaf(rW[7],  b.w, o);
  o = fmaf(rW[8],  c.x, o); o = fmaf(rW[9],  c.y, o);
  o = fmaf(rW[10], c.z, o); o = fmaf(rW[11], c.w, o);
  o = fmaf(rW[12], d.x, o); o = fmaf(rW[13], d.y, o);
  o = fmaf(rW[14], d.z, o); o = fmaf(rW[15], d.w, o);
  return o;
}

// One wave (64 lanes) per batch element; block = 1 wave => no barriers.
// y LDS round trip eliminated using ONLY session-verified primitives:
// y_own is quad-replicated (quad Q = l>>2 holds y[Q]); lane l's half-dot
// needs y[Q^j], j=0..7 (same bit3 as Q -> never crosses the 32-lane half):
//   j=1: DPP row_half_mirror (0x141)   j=2: DPP row_ror:8 (lane^8, 0x128)
//   j=3: DPP row_mirror (0x140)        j=4..7: ds_bpermute idx=4*(l^16) of
//                                      the j-4 values (R5-verified class).
// Weight columns are XOR-clean: Wy[j] = W1[row][1 + (Q^j)] - no orientation
// conditionals (the permlane16_swap of R7/R8 is gone).
// The gather for step n+1 is issued at the BOTTOM of step n (right after the
// y update) and carried in registers, so DS latency hides under loop-back.
// The s round trip through LDS remains. Everything else verbatim R6.
__global__ __launch_bounds__(64) void disc_kernel(
    const float* __restrict__ ts, const float* __restrict__ ys,
    const float* __restrict__ iW1, const float* __restrict__ ib1,
    const float* __restrict__ iW2, const float* __restrict__ ib2,
    const float* __restrict__ vW1, const float* __restrict__ vb1,
    const float* __restrict__ vW2, const float* __restrict__ vb2,
    const float* __restrict__ cW1, const float* __restrict__ cb1,
    const float* __restrict__ cW2, const float* __restrict__ cb2,
    const float* __restrict__ rW, const float* __restrict__ rb,
    float* __restrict__ out)
{
  const int b    = blockIdx.x;
  const int l    = threadIdx.x;
  const int h16  = l & 15;
  const int p    = (l >> 4) & 1;
  const int hf   = l >> 2;           // quad Q == y index held
  const int d0   = (2 * l) & 7;
  const int q4   = 4 * (l & 3);      // f-quartet base (s_f columns)
  const int idx16 = 4 * (l ^ 16);    // bpermute index for lane^16
  const int ywslot = ((l & 3) == 0) ? (64 + hf) : (80 + l);  // final y publish

  __shared__ __align__(16) float sbuf[16];    // init relu staging
  __shared__ __align__(16) float cbuf[160];   // [0..63] s, [64..79] y, [80..143] dump
  __shared__ __align__(16) float xbuf[1040];  // 2 x 64 dx-rows (8 floats) + pad

  const float* __restrict__ ysb = ys + (size_t)b * (T_LEN * 8);

  const float NL2E = -1.4426950408889634f;                 // -log2(e)
  const float TSW  = 2.0f * 1.4426950408889634f * 0.909f;  // weight scale (tanh arg)
  const float TSB  = 2.0f * 1.4426950408889634f;           // bias scale (tanh arg)

  // ---- per-lane weights (scaled) ----
  // layer-1 row (p, h16); col for gathered value y[Q^j] is simply 1 + (Q^j).
  float w1t, b1m;
  float Wy[8];
  {
    const float* W1 = p ? cW1 : vW1;
    const float* bv = p ? cb1 : vb1;
    w1t = NL2E * W1[h16 * 17];
    b1m = NL2E * bv[h16];
    const int Q = l >> 2;
#pragma unroll
    for (int j = 0; j < 8; ++j)
      Wy[j] = NL2E * W1[h16 * 17 + 1 + (Q ^ j)];
    if (l >= 32) { w1t = 0.0f; b1m = 0.0f; }  // t/bias counted once (low half)
  }
  v2f W2q[2];
#pragma unroll
  for (int j = 0; j < 2; ++j) {
    v2f w; w.x = TSW * vW2[hf * 16 + q4 + 2 * j];
           w.y = TSW * vW2[hf * 16 + q4 + 2 * j + 1];
    W2q[j] = w;
  }
  v2f G0p[8], G1p[8];
#pragma unroll
  for (int k = 0; k < 8; ++k) {
    v2f c0; c0.x = TSW * cW2[(2 * l) * 16 + 2 * k]; c0.y = TSW * cW2[(2 * l) * 16 + 2 * k + 1];
    G0p[k] = c0;
    v2f c1; c1.x = TSW * cW2[(2 * l + 1) * 16 + 2 * k]; c1.y = TSW * cW2[(2 * l + 1) * 16 + 2 * k + 1];
    G1p[k] = c1;
  }
  const float b2p  = TSB * vb2[hf];
  const float bg0p = TSB * cb2[2 * l];
  const float bg1p = TSB * cb2[2 * l + 1];

  const float t0 = ts[0];

  // ---- initial hidden state (cold path, via LDS; same-wave DS is ordered) ----
  float y_own;
  {
    float acc = ib1[h16] + iW1[h16 * 9] * t0;
#pragma unroll
    for (int d = 0; d < 8; ++d) acc = fmaf(iW1[h16 * 9 + 1 + d], ysb[d], acc);
    sbuf[h16] = fmaxf(acc, 0.0f);
    cfence();
    float acc2 = ib2[h16];
#pragma unroll
    for (int k = 0; k < 16; ++k) acc2 = fmaf(iW2[h16 * 16 + k], sbuf[k], acc2);
    cbuf[64 + h16] = acc2;     // duplicate same-addr same-value writes (init only)
    cfence();
    y_own = cbuf[64 + hf];     // quad-replicated y[Q]
  }

  // ---- readout at t0 ----
  {
    const float o = readout_lds(cbuf, rW, rb[0]);
    if (l == 0) out[2 * b] = o;
  }

  // ---- dx staging: 64-row chunks, double-buffered, prefetch next chunk ----
  const int CLAMP = T_LEN * 8 - 4;
  float4 A, Bq, Cq, Dq;
  {
    const int f0 = l * 8;
    A  = *(const float4*)(ysb + min(f0,      CLAMP));
    Bq = *(const float4*)(ysb + min(f0 + 4,  CLAMP));
    Cq = *(const float4*)(ysb + min(f0 + 8,  CLAMP));
    Dq = *(const float4*)(ysb + min(f0 + 12, CLAMP));
    float4 e0, e1;
    e0.x = Cq.x - A.x;  e0.y = Cq.y - A.y;  e0.z = Cq.z - A.z;  e0.w = Cq.w - A.w;
    e1.x = Dq.x - Bq.x; e1.y = Dq.y - Bq.y; e1.z = Dq.z - Bq.z; e1.w = Dq.w - Bq.w;
    *(float4*)(xbuf + l * 8)     = e0;
    *(float4*)(xbuf + l * 8 + 4) = e1;
    cfence();
  }

  // ---- prime pipelined dx + y-gather ----
  v2f dxc = *(const v2f*)(xbuf + d0);
  float yg0, yg1, yg2, yg3, yg4, yg5, yg6, yg7;
  {
    yg0 = y_own;
    yg1 = dpp_movf<0x141>(y_own);  // y[Q^1]
    yg2 = dpp_movf<0x128>(y_own);  // y[Q^2] (lane^8)
    yg3 = dpp_movf<0x140>(y_own);  // y[Q^3]
    yg4 = bperm(idx16, yg0);       // y[Q^4]
    yg5 = bperm(idx16, yg1);       // y[Q^5]
    yg6 = bperm(idx16, yg2);       // y[Q^6]
    yg7 = bperm(idx16, yg3);       // y[Q^7]
  }

  float t = t0;
  for (int c = 0; c < 64; ++c) {
    // prefetch chunk c+1 (clamped; last chunk re-reads itself, harmless)
    {
      const int cn = min(c + 1, 63);
      const int f0 = cn * 512 + l * 8;
      A  = *(const float4*)(ysb + min(f0,      CLAMP));
      Bq = *(const float4*)(ysb + min(f0 + 4,  CLAMP));
      Cq = *(const float4*)(ysb + min(f0 + 8,  CLAMP));
      Dq = *(const float4*)(ysb + min(f0 + 12, CLAMP));
    }
    const float* __restrict__ xb = xbuf + (c & 1) * 512;
    const int base = c * 64;
    const int nsteps = min(64, (T_LEN - 1) - base);
    for (int j = 0; j < nsteps; ++j) {
      const v2f dx = dxc;   // pipelined from previous step's bottom

      // layer-1 half-dot on carried gathered y (8 fma, 2 chains), then merge
      const float m_t = fmaf(w1t, t, b1m);
      float aca = fmaf(Wy[0], yg0, m_t);
      float acb = Wy[1] * yg1;
      aca = fmaf(Wy[2], yg2, aca);
      acb = fmaf(Wy[3], yg3, acb);
      aca = fmaf(Wy[4], yg4, aca);
      acb = fmaf(Wy[5], yg5, acb);
      aca = fmaf(Wy[6], yg6, aca);
      acb = fmaf(Wy[7], yg7, acb);
      const float m = half_sum(aca + acb);

      // silu: u * sigmoid(u), u = -ln2 * m, exp(-u) = exp2(m)
      const float eM = fexp2(m);
      const float s  = (m * NLN2f) * frcp(1.0f + eM);

      // publish s; fenced so broadcast reads can't be hoisted above the write
      cbuf[l] = s;
      cfence();
      const v4f g0 = *(const v4f*)(cbuf + 16);   // s_g[0..3]   (uniform bcast)
      const v4f g1 = *(const v4f*)(cbuf + 20);   // s_g[4..7]
      const v4f g2 = *(const v4f*)(cbuf + 24);   // s_g[8..11]
      const v4f g3 = *(const v4f*)(cbuf + 28);   // s_g[12..15]
      const v4f sf = *(const v4f*)(cbuf + q4);   // s_f quartet (4-addr bcast)

      // g-dots: 2 rows x 16, two chains each (all-VGPR pk)
      v2f ga; ga.x = bg0p; ga.y = 0.0f;
      v2f gc; gc.x = 0.0f; gc.y = 0.0f;
      v2f gb; gb.x = bg1p; gb.y = 0.0f;
      v2f gd; gd.x = 0.0f; gd.y = 0.0f;
      pk_fma_v(ga, G0p[0], g0.xy); pk_fma_v(ga, G0p[1], g0.zw);
      pk_fma_v(ga, G0p[2], g1.xy); pk_fma_v(ga, G0p[3], g1.zw);
      pk_fma_v(gc, G0p[4], g2.xy); pk_fma_v(gc, G0p[5], g2.zw);
      pk_fma_v(gc, G0p[6], g3.xy); pk_fma_v(gc, G0p[7], g3.zw);
      pk_fma_v(gb, G1p[0], g0.xy); pk_fma_v(gb, G1p[1], g0.zw);
      pk_fma_v(gb, G1p[2], g1.xy); pk_fma_v(gb, G1p[3], g1.zw);
      pk_fma_v(gd, G1p[4], g2.xy); pk_fma_v(gd, G1p[5], g2.zw);
      pk_fma_v(gd, G1p[6], g3.xy); pk_fma_v(gd, G1p[7], g3.zw);

      // f quarter-dot + quad butterfly BEFORE tanh (bias once, post-reduce)
      v2f fa; fa.x = 0.0f; fa.y = 0.0f;
      pk_fma_v(fa, W2q[0], sf.xy);
      pk_fma_v(fa, W2q[1], sf.zw);
      float fp = fa.x + fa.y;
      fp = dpp_add<0xB1>(fp);
      fp = dpp_add<0x4E>(fp);
      const float farg = fp + b2p;

      // tanh(x) = 1 - 2/(1+exp2(x')) with x' pre-scaled by 2*log2e
      const v2f gs0 = ga + gc;
      const v2f gs1 = gb + gd;
      const float g0v = fmaf(-2.0f, frcp(1.0f + fexp2(gs0.x + gs0.y)), 1.0f);
      const float g1v = fmaf(-2.0f, frcp(1.0f + fexp2(gs1.x + gs1.y)), 1.0f);
      const float fv  = fmaf(-2.0f, frcp(1.0f + fexp2(farg)), 1.0f);

      // einsum partial + quad butterfly reduce over d
      float pr = fmaf(g0v, dx.x, g1v * dx.y);
      pr = dpp_add<0xB1>(pr);
      pr = dpp_add<0x4E>(pr);

      y_own = y_own + (fv + pr);   // stays quad-replicated (fv, pr quad-uniform)

      // ---- bottom-of-step: issue next step's y-gather + dx (latency hides
      // under loop-back + top-of-step issue) ----
      yg0 = y_own;
      yg1 = dpp_movf<0x141>(y_own);
      yg2 = dpp_movf<0x128>(y_own);
      yg3 = dpp_movf<0x140>(y_own);
      yg4 = bperm(idx16, yg0);
      yg5 = bperm(idx16, yg1);
      yg6 = bperm(idx16, yg2);
      yg7 = bperm(idx16, yg3);
      dxc = *(const v2f*)(xb + (j + 1) * 8 + d0);  // j+1==64 -> pad; fixed below
      t += 1.0f;
    }
    // write prefetched chunk into the other buffer (vmcnt drain is off the
    // step critical path: 64 steps of compute covered the load latency)
    float* xbn = xbuf + ((c + 1) & 1) * 512;
    float4 e0, e1;
    e0.x = Cq.x - A.x;  e0.y = Cq.y - A.y;  e0.z = Cq.z - A.z;  e0.w = Cq.w - A.w;
    e1.x = Dq.x - Bq.x; e1.y = Dq.y - Bq.y; e1.z = Dq.z - Bq.z; e1.w = Dq.w - Bq.w;
    *(float4*)(xbn + l * 8)     = e0;
    *(float4*)(xbn + l * 8 + 4) = e1;
    cfence();
    // correct the pipelined dx for the first step of the next chunk
    dxc = *(const v2f*)(xbn + d0);
  }

  // ---- publish final y once, then readout at t1 ----
  cbuf[ywslot] = y_own;     // (l&3)==0 lanes -> real slots, rest -> dump region
  cfence();
  {
    const float o = readout_lds(cbuf, rW, rb[0]);
    if (l == 0) out[2 * b + 1] = o;
  }
}

extern "C" void kernel_launch(void* const* d_in, const int* in_sizes, int n_in,
                              void* d_out, int out_size, void* d_ws, size_t ws_size,
                              hipStream_t stream) {
  (void)in_sizes; (void)n_in; (void)out_size; (void)d_ws; (void)ws_size;
  const float* ts  = (const float*)d_in[0];
  const float* ys  = (const float*)d_in[1];
  const float* iW1 = (const float*)d_in[2];
  const float* ib1 = (const float*)d_in[3];
  const float* iW2 = (const float*)d_in[4];
  const float* ib2 = (const float*)d_in[5];
  const float* vW1 = (const float*)d_in[6];
  const float* vb1 = (const float*)d_in[7];
  const float* vW2 = (const float*)d_in[8];
  const float* vb2 = (const float*)d_in[9];
  const float* cW1 = (const float*)d_in[10];
  const float* cb1 = (const float*)d_in[11];
  const float* cW2 = (const float*)d_in[12];
  const float* cb2 = (const float*)d_in[13];
  const float* rW  = (const float*)d_in[14];
  const float* rb  = (const float*)d_in[15];
  float* out = (float*)d_out;
  hipLaunchKernelGGL(disc_kernel, dim3(512), dim3(64), 0, stream,
                     ts, ys, iW1, ib1, iW2, ib2, vW1, vb1, vW2, vb2,
                     cW1, cb1, cW2, cb2, rW, rb, out);
}

// Round 11
// 1005.035 us; speedup vs baseline: 1.9293x; 1.0998x over previous
//
#include <hip/hip_runtime.h>

#define T_LEN 4096

typedef float v2f __attribute__((ext_vector_type(2)));
typedef float v4f __attribute__((ext_vector_type(4)));

__device__ __forceinline__ float frcp(float x) { return __builtin_amdgcn_rcpf(x); }
__device__ __forceinline__ float fexp2(float x) { return __builtin_amdgcn_exp2f(x); }

// packed dual-FMA: acc = w*s + acc (VOP3P, full-rate fp32 pairs, all-VGPR).
__device__ __forceinline__ void pk_fma_v(v2f& acc, v2f w, v2f s) {
  asm("v_pk_fma_f32 %0, %1, %2, %0" : "+v"(acc) : "v"(w), "v"(s));
}
// packed mul: acc = w*s (accumulator START - kills the mov-pair init).
__device__ __forceinline__ v2f pk_mul_v(v2f w, v2f s) {
  v2f r;
  asm("v_pk_mul_f32 %0, %1, %2" : "=v"(r) : "v"(w), "v"(s));
  return r;
}
// packed add (guarantees 1 VOP3P instr, not 2 scalar adds).
__device__ __forceinline__ v2f pk_add_v(v2f a, v2f b) {
  v2f r;
  asm("v_pk_add_f32 %0, %1, %2" : "=v"(r) : "v"(a), "v"(b));
  return r;
}

// quad_perm DPP butterfly adds: xor1 = 0xB1, xor2 = 0x4E
template <int CTRL>
__device__ __forceinline__ float dpp_add(float x) {
  int t = __builtin_amdgcn_mov_dpp(__float_as_int(x), CTRL, 0xF, 0xF, true);
  return x + __int_as_float(t);
}
template <int CTRL>
__device__ __forceinline__ float dpp_movf(float x) {
  return __int_as_float(
      __builtin_amdgcn_mov_dpp(__float_as_int(x), CTRL, 0xF, 0xF, true));
}

// register cross-lane gather (verified R5/R9): returns v from lane (idx/4).
__device__ __forceinline__ float bperm(int idx, float v) {
  return __int_as_float(__builtin_amdgcn_ds_bpermute(idx, __float_as_int(v)));
}

// cross-half (lanes l <-> l^32) sum via permlane32_swap; orientation-immune
// because the result is a+b. Proven in R6/R9.
__device__ __forceinline__ float half_sum(float x) {
  float a = x, b;
  asm("v_mov_b32 %1, %0\n\t"
      "v_permlane32_swap_b32 %0, %1"
      : "+v"(a), "=&v"(b));
  return a + b;
}

// compile-time fence: forbids reordering LDS publish vs dependent broadcast
// reads (float stores vs v4f reinterpret loads could be TBAA-noalias).
__device__ __forceinline__ void cfence() { asm volatile("" ::: "memory"); }

#define NLN2f (-0.6931471805599453f)

// readout: y[0..15] lives in cb[64..79]; all lanes compute (uniform), lane 0 stores.
__device__ __forceinline__ float readout_lds(const float* cb,
                                             const float* __restrict__ rW,
                                             float rb0) {
  v4f a = *(const v4f*)(cb + 64);
  v4f b = *(const v4f*)(cb + 68);
  v4f c = *(const v4f*)(cb + 72);
  v4f d = *(const v4f*)(cb + 76);
  float o = rb0;
  o = fmaf(rW[0],  a.x, o); o = fmaf(rW[1],  a.y, o);
  o = fmaf(rW[2],  a.z, o); o = fmaf(rW[3],  a.w, o);
  o = fmaf(rW[4],  b.x, o); o = fmaf(rW[5],  b.y, o);
  o = fmaf(rW[6],  b.z, o); o = fmaf(rW[7],  b.w, o);
  o = fmaf(rW[8],  c.x, o); o = fmaf(rW[9],  c.y, o);
  o = fmaf(rW[10], c.z, o); o = fmaf(rW[11], c.w, o);
  o = fmaf(rW[12], d.x, o); o = fmaf(rW[13], d.y, o);
  o = fmaf(rW[14], d.z, o); o = fmaf(rW[15], d.w, o);
  return o;
}

// One wave (64 lanes) per batch element; block = 1 wave => no barriers.
// R9 structure (y via quad-DPP + direct-index ds_bpermute; s via one LDS
// round trip) with the SAFE part of the R10 instruction diet:
//  - accumulators start with v_pk_mul (no mov-pair inits); biases fold into
//    the post-reduce scalar adds (bounded reassociation).
//  - gs merges via explicit v_pk_add.
//  - yg4..7 gathered straight from y_own with precomputed indices
//    4*(l^16),4*(l^20),4*(l^24),4*(l^28).
//  - inner loop unrolled x4 over constant 64-step chunks (63-step tail).
// The R10 incremental m_acc is REVERTED (4095 serial adds drifted ~0.1 in
// the silu arg -> absmax 224): m_t = fmaf(w1t, t, b1m) is exact per step.
__global__ __launch_bounds__(64) void disc_kernel(
    const float* __restrict__ ts, const float* __restrict__ ys,
    const float* __restrict__ iW1, const float* __restrict__ ib1,
    const float* __restrict__ iW2, const float* __restrict__ ib2,
    const float* __restrict__ vW1, const float* __restrict__ vb1,
    const float* __restrict__ vW2, const float* __restrict__ vb2,
    const float* __restrict__ cW1, const float* __restrict__ cb1,
    const float* __restrict__ cW2, const float* __restrict__ cb2,
    const float* __restrict__ rW, const float* __restrict__ rb,
    float* __restrict__ out)
{
  const int b    = blockIdx.x;
  const int l    = threadIdx.x;
  const int h16  = l & 15;
  const int p    = (l >> 4) & 1;
  const int hf   = l >> 2;           // quad Q == y index held
  const int d0   = (2 * l) & 7;
  const int q4   = 4 * (l & 3);      // f-quartet base (s_f columns)
  const int ixA = 4 * (l ^ 16);      // y[Q^4]
  const int ixB = 4 * (l ^ 20);      // y[Q^5]
  const int ixC = 4 * (l ^ 24);      // y[Q^6]
  const int ixD = 4 * (l ^ 28);      // y[Q^7]
  const int ywslot = ((l & 3) == 0) ? (64 + hf) : (80 + l);  // final y publish

  __shared__ __align__(16) float sbuf[16];    // init relu staging
  __shared__ __align__(16) float cbuf[160];   // [0..63] s, [64..79] y, [80..143] dump
  __shared__ __align__(16) float xbuf[1040];  // 2 x 64 dx-rows (8 floats) + pad

  const float* __restrict__ ysb = ys + (size_t)b * (T_LEN * 8);

  const float NL2E = -1.4426950408889634f;                 // -log2(e)
  const float TSW  = 2.0f * 1.4426950408889634f * 0.909f;  // weight scale (tanh arg)
  const float TSB  = 2.0f * 1.4426950408889634f;           // bias scale (tanh arg)

  // ---- per-lane weights (scaled) ----
  float w1t, b1m;
  float Wy[8];
  {
    const float* W1 = p ? cW1 : vW1;
    const float* bv = p ? cb1 : vb1;
    w1t = NL2E * W1[h16 * 17];
    b1m = NL2E * bv[h16];
    const int Q = l >> 2;
#pragma unroll
    for (int j = 0; j < 8; ++j)
      Wy[j] = NL2E * W1[h16 * 17 + 1 + (Q ^ j)];
    if (l >= 32) { w1t = 0.0f; b1m = 0.0f; }  // t/bias counted once (low half)
  }
  v2f W2q[2];
#pragma unroll
  for (int j = 0; j < 2; ++j) {
    v2f w; w.x = TSW * vW2[hf * 16 + q4 + 2 * j];
           w.y = TSW * vW2[hf * 16 + q4 + 2 * j + 1];
    W2q[j] = w;
  }
  v2f G0p[8], G1p[8];
#pragma unroll
  for (int k = 0; k < 8; ++k) {
    v2f c0; c0.x = TSW * cW2[(2 * l) * 16 + 2 * k]; c0.y = TSW * cW2[(2 * l) * 16 + 2 * k + 1];
    G0p[k] = c0;
    v2f c1; c1.x = TSW * cW2[(2 * l + 1) * 16 + 2 * k]; c1.y = TSW * cW2[(2 * l + 1) * 16 + 2 * k + 1];
    G1p[k] = c1;
  }
  const float b2p  = TSB * vb2[hf];
  const float bg0p = TSB * cb2[2 * l];
  const float bg1p = TSB * cb2[2 * l + 1];

  const float t0 = ts[0];

  // ---- initial hidden state (cold path, via LDS; same-wave DS is ordered) ----
  float y_own;
  {
    float acc = ib1[h16] + iW1[h16 * 9] * t0;
#pragma unroll
    for (int d = 0; d < 8; ++d) acc = fmaf(iW1[h16 * 9 + 1 + d], ysb[d], acc);
    sbuf[h16] = fmaxf(acc, 0.0f);
    cfence();
    float acc2 = ib2[h16];
#pragma unroll
    for (int k = 0; k < 16; ++k) acc2 = fmaf(iW2[h16 * 16 + k], sbuf[k], acc2);
    cbuf[64 + h16] = acc2;     // duplicate same-addr same-value writes (init only)
    cfence();
    y_own = cbuf[64 + hf];     // quad-replicated y[Q]
  }

  // ---- readout at t0 ----
  {
    const float o = readout_lds(cbuf, rW, rb[0]);
    if (l == 0) out[2 * b] = o;
  }

  // ---- dx staging: 64-row chunks, double-buffered, prefetch next chunk ----
  const int CLAMP = T_LEN * 8 - 4;
  float4 A, Bq, Cq, Dq;
  {
    const int f0 = l * 8;
    A  = *(const float4*)(ysb + min(f0,      CLAMP));
    Bq = *(const float4*)(ysb + min(f0 + 4,  CLAMP));
    Cq = *(const float4*)(ysb + min(f0 + 8,  CLAMP));
    Dq = *(const float4*)(ysb + min(f0 + 12, CLAMP));
    float4 e0, e1;
    e0.x = Cq.x - A.x;  e0.y = Cq.y - A.y;  e0.z = Cq.z - A.z;  e0.w = Cq.w - A.w;
    e1.x = Dq.x - Bq.x; e1.y = Dq.y - Bq.y; e1.z = Dq.z - Bq.z; e1.w = Dq.w - Bq.w;
    *(float4*)(xbuf + l * 8)     = e0;
    *(float4*)(xbuf + l * 8 + 4) = e1;
    cfence();
  }

  // ---- prime pipelined state: dx + y-gather ----
  v2f dxc = *(const v2f*)(xbuf + d0);
  float yg1 = dpp_movf<0x141>(y_own);  // y[Q^1]
  float yg2 = dpp_movf<0x128>(y_own);  // y[Q^2] (lane^8)
  float yg3 = dpp_movf<0x140>(y_own);  // y[Q^3]
  float yg4 = bperm(ixA, y_own);       // y[Q^4]
  float yg5 = bperm(ixB, y_own);       // y[Q^5]
  float yg6 = bperm(ixC, y_own);       // y[Q^6]
  float yg7 = bperm(ixD, y_own);       // y[Q^7]
  float t = t0;

  // ---- one simulation step (macro so unrolled bodies stay register-clean) ----
#define STEP(XB, JNEXT)                                                        \
  {                                                                            \
    const v2f dx = dxc;                                                        \
    const float m_t = fmaf(w1t, t, b1m);                                       \
    float aca = fmaf(Wy[0], y_own, m_t);                                       \
    float acb = Wy[1] * yg1;                                                   \
    aca = fmaf(Wy[2], yg2, aca);                                               \
    acb = fmaf(Wy[3], yg3, acb);                                               \
    aca = fmaf(Wy[4], yg4, aca);                                               \
    acb = fmaf(Wy[5], yg5, acb);                                               \
    aca = fmaf(Wy[6], yg6, aca);                                               \
    acb = fmaf(Wy[7], yg7, acb);                                               \
    const float m = half_sum(aca + acb);                                       \
    const float eM = fexp2(m);                                                 \
    const float s  = (m * NLN2f) * frcp(1.0f + eM);                            \
    cbuf[l] = s;                                                               \
    cfence();                                                                  \
    const v4f g0 = *(const v4f*)(cbuf + 16);                                   \
    const v4f g1 = *(const v4f*)(cbuf + 20);                                   \
    const v4f g2 = *(const v4f*)(cbuf + 24);                                   \
    const v4f g3 = *(const v4f*)(cbuf + 28);                                   \
    const v4f sf = *(const v4f*)(cbuf + q4);                                   \
    v2f ga = pk_mul_v(G0p[0], g0.xy);                                          \
    v2f gb = pk_mul_v(G1p[0], g0.xy);                                          \
    v2f gc = pk_mul_v(G0p[4], g2.xy);                                          \
    v2f gd = pk_mul_v(G1p[4], g2.xy);                                          \
    pk_fma_v(ga, G0p[1], g0.zw); pk_fma_v(gb, G1p[1], g0.zw);                  \
    pk_fma_v(ga, G0p[2], g1.xy); pk_fma_v(gb, G1p[2], g1.xy);                  \
    pk_fma_v(ga, G0p[3], g1.zw); pk_fma_v(gb, G1p[3], g1.zw);                  \
    pk_fma_v(gc, G0p[5], g2.zw); pk_fma_v(gd, G1p[5], g2.zw);                  \
    pk_fma_v(gc, G0p[6], g3.xy); pk_fma_v(gd, G1p[6], g3.xy);                  \
    pk_fma_v(gc, G0p[7], g3.zw); pk_fma_v(gd, G1p[7], g3.zw);                  \
    v2f fa = pk_mul_v(W2q[0], sf.xy);                                          \
    pk_fma_v(fa, W2q[1], sf.zw);                                               \
    float fp = fa.x + fa.y;                                                    \
    fp = dpp_add<0xB1>(fp);                                                    \
    fp = dpp_add<0x4E>(fp);                                                    \
    const float farg = fp + b2p;                                               \
    const v2f gs0 = pk_add_v(ga, gc);                                          \
    const v2f gs1 = pk_add_v(gb, gd);                                          \
    const float g0v = fmaf(-2.0f, frcp(1.0f + fexp2(gs0.x + gs0.y + bg0p)), 1.0f); \
    const float g1v = fmaf(-2.0f, frcp(1.0f + fexp2(gs1.x + gs1.y + bg1p)), 1.0f); \
    const float fv  = fmaf(-2.0f, frcp(1.0f + fexp2(farg)), 1.0f);             \
    float pr = fmaf(g0v, dx.x, g1v * dx.y);                                    \
    pr = dpp_add<0xB1>(pr);                                                    \
    pr = dpp_add<0x4E>(pr);                                                    \
    y_own = y_own + (fv + pr);                                                 \
    yg1 = dpp_movf<0x141>(y_own);                                              \
    yg2 = dpp_movf<0x128>(y_own);                                              \
    yg3 = dpp_movf<0x140>(y_own);                                              \
    yg4 = bperm(ixA, y_own);                                                   \
    yg5 = bperm(ixB, y_own);                                                   \
    yg6 = bperm(ixC, y_own);                                                   \
    yg7 = bperm(ixD, y_own);                                                   \
    dxc = *(const v2f*)((XB) + (JNEXT) * 8 + d0);                              \
    t += 1.0f;                                                                 \
  }

  // ---- chunks 0..62: constant 64 steps, unrolled x4 ----
  for (int c = 0; c < 63; ++c) {
    {
      const int f0 = (c + 1) * 512 + l * 8;
      A  = *(const float4*)(ysb + min(f0,      CLAMP));
      Bq = *(const float4*)(ysb + min(f0 + 4,  CLAMP));
      Cq = *(const float4*)(ysb + min(f0 + 8,  CLAMP));
      Dq = *(const float4*)(ysb + min(f0 + 12, CLAMP));
    }
    const float* __restrict__ xb = xbuf + (c & 1) * 512;
#pragma unroll 4
    for (int j = 0; j < 64; ++j) {
      STEP(xb, j + 1)   // j+1==64 reads pad/other buffer; corrected below
    }
    float* xbn = xbuf + ((c + 1) & 1) * 512;
    float4 e0, e1;
    e0.x = Cq.x - A.x;  e0.y = Cq.y - A.y;  e0.z = Cq.z - A.z;  e0.w = Cq.w - A.w;
    e1.x = Dq.x - Bq.x; e1.y = Dq.y - Bq.y; e1.z = Dq.z - Bq.z; e1.w = Dq.w - Bq.w;
    *(float4*)(xbn + l * 8)     = e0;
    *(float4*)(xbn + l * 8 + 4) = e1;
    cfence();
    dxc = *(const v2f*)(xbn + d0);   // correct first-step dx of next chunk
  }
  // ---- tail chunk 63: 63 steps (rows 4032..4094) ----
  {
    const float* __restrict__ xb = xbuf + 512;  // chunk 63 buffer (63&1 = 1)
    for (int j = 0; j < 63; ++j) {
      STEP(xb, min(j + 1, 63))
    }
  }
#undef STEP

  // ---- publish final y once, then readout at t1 ----
  cbuf[ywslot] = y_own;     // (l&3)==0 lanes -> real slots, rest -> dump region
  cfence();
  {
    const float o = readout_lds(cbuf, rW, rb[0]);
    if (l == 0) out[2 * b + 1] = o;
  }
}

extern "C" void kernel_launch(void* const* d_in, const int* in_sizes, int n_in,
                              void* d_out, int out_size, void* d_ws, size_t ws_size,
                              hipStream_t stream) {
  (void)in_sizes; (void)n_in; (void)out_size; (void)d_ws; (void)ws_size;
  const float* ts  = (const float*)d_in[0];
  const float* ys  = (const float*)d_in[1];
  const float* iW1 = (const float*)d_in[2];
  const float* ib1 = (const float*)d_in[3];
  const float* iW2 = (const float*)d_in[4];
  const float* ib2 = (const float*)d_in[5];
  const float* vW1 = (const float*)d_in[6];
  const float* vb1 = (const float*)d_in[7];
  const float* vW2 = (const float*)d_in[8];
  const float* vb2 = (const float*)d_in[9];
  const float* cW1 = (const float*)d_in[10];
  const float* cb1 = (const float*)d_in[11];
  const float* cW2 = (const float*)d_in[12];
  const float* cb2 = (const float*)d_in[13];
  const float* rW  = (const float*)d_in[14];
  const float* rb  = (const float*)d_in[15];
  float* out = (float*)d_out;
  hipLaunchKernelGGL(disc_kernel, dim3(512), dim3(64), 0, stream,
                     ts, ys, iW1, ib1, iW2, ib2, vW1, vb1, vW2, vb2,
                     cW1, cb1, cW2, cb2, rW, rb, out);
}

// Round 12
// 995.972 us; speedup vs baseline: 1.9469x; 1.0091x over previous
//
#include <hip/hip_runtime.h>

#define T_LEN 4096

typedef float v2f __attribute__((ext_vector_type(2)));
typedef float v4f __attribute__((ext_vector_type(4)));

__device__ __forceinline__ float frcp(float x) { return __builtin_amdgcn_rcpf(x); }
__device__ __forceinline__ float fexp2(float x) { return __builtin_amdgcn_exp2f(x); }

// packed dual-FMA: acc = w*s + acc (VOP3P, full-rate fp32 pairs, all-VGPR).
__device__ __forceinline__ void pk_fma_v(v2f& acc, v2f w, v2f s) {
  asm("v_pk_fma_f32 %0, %1, %2, %0" : "+v"(acc) : "v"(w), "v"(s));
}
// non-destructive packed FMA: r = w*s + c (accumulator START with bias -
// kills the mov-pair init AND keeps the bias off the tanh critical path).
__device__ __forceinline__ v2f pk_fma_nv(v2f w, v2f s, v2f c) {
  v2f r;
  asm("v_pk_fma_f32 %0, %1, %2, %3" : "=v"(r) : "v"(w), "v"(s), "v"(c));
  return r;
}
// packed mul: acc = w*s (bias-free accumulator START).
__device__ __forceinline__ v2f pk_mul_v(v2f w, v2f s) {
  v2f r;
  asm("v_pk_mul_f32 %0, %1, %2" : "=v"(r) : "v"(w), "v"(s));
  return r;
}
// packed add (guarantees 1 VOP3P instr, not 2 scalar adds).
__device__ __forceinline__ v2f pk_add_v(v2f a, v2f b) {
  v2f r;
  asm("v_pk_add_f32 %0, %1, %2" : "=v"(r) : "v"(a), "v"(b));
  return r;
}

// quad_perm DPP butterfly adds: xor1 = 0xB1, xor2 = 0x4E
template <int CTRL>
__device__ __forceinline__ float dpp_add(float x) {
  int t = __builtin_amdgcn_mov_dpp(__float_as_int(x), CTRL, 0xF, 0xF, true);
  return x + __int_as_float(t);
}
template <int CTRL>
__device__ __forceinline__ float dpp_movf(float x) {
  return __int_as_float(
      __builtin_amdgcn_mov_dpp(__float_as_int(x), CTRL, 0xF, 0xF, true));
}

// register cross-lane gather (verified R5/R9): returns v from lane (idx/4).
__device__ __forceinline__ float bperm(int idx, float v) {
  return __int_as_float(__builtin_amdgcn_ds_bpermute(idx, __float_as_int(v)));
}

// cross-half (lanes l <-> l^32) sum via permlane32_swap; orientation-immune
// because the result is a+b. Proven in R6/R9/R11.
__device__ __forceinline__ float half_sum(float x) {
  float a = x, b;
  asm("v_mov_b32 %1, %0\n\t"
      "v_permlane32_swap_b32 %0, %1"
      : "+v"(a), "=&v"(b));
  return a + b;
}

// compile-time fence: forbids reordering LDS publish vs dependent broadcast
// reads (float stores vs v4f reinterpret loads could be TBAA-noalias).
__device__ __forceinline__ void cfence() { asm volatile("" ::: "memory"); }

#define NLN2f (-0.6931471805599453f)

// readout: y[0..15] lives in cb[64..79]; all lanes compute (uniform), lane 0 stores.
__device__ __forceinline__ float readout_lds(const float* cb,
                                             const float* __restrict__ rW,
                                             float rb0) {
  v4f a = *(const v4f*)(cb + 64);
  v4f b = *(const v4f*)(cb + 68);
  v4f c = *(const v4f*)(cb + 72);
  v4f d = *(const v4f*)(cb + 76);
  float o = rb0;
  o = fmaf(rW[0],  a.x, o); o = fmaf(rW[1],  a.y, o);
  o = fmaf(rW[2],  a.z, o); o = fmaf(rW[3],  a.w, o);
  o = fmaf(rW[4],  b.x, o); o = fmaf(rW[5],  b.y, o);
  o = fmaf(rW[6],  b.z, o); o = fmaf(rW[7],  b.w, o);
  o = fmaf(rW[8],  c.x, o); o = fmaf(rW[9],  c.y, o);
  o = fmaf(rW[10], c.z, o); o = fmaf(rW[11], c.w, o);
  o = fmaf(rW[12], d.x, o); o = fmaf(rW[13], d.y, o);
  o = fmaf(rW[14], d.z, o); o = fmaf(rW[15], d.w, o);
  return o;
}

// One wave (64 lanes) per batch element; block = 1 wave => no barriers.
// R11 structure (y via quad-DPP + direct-index ds_bpermute; s via one LDS
// round trip; pk_mul/pk_add diet; x4 unroll) with bias-folding:
//  - ga/gb start as r = G*s + {bias,0} via non-destructive v_pk_fma
//    (restores the verified R9 bias-in-accumulator numerics, removes the
//    two bias adds from the g->tanh critical path).
//  - fa starts as r = W*s + {0.25*b2p, 0}: quad butterfly sums 4 lanes so
//    the bias totals b2p (bounded reassociation); removes the farg add.
//  - dx load hoisted above the y-gather issue at step bottom.
__global__ __launch_bounds__(64) void disc_kernel(
    const float* __restrict__ ts, const float* __restrict__ ys,
    const float* __restrict__ iW1, const float* __restrict__ ib1,
    const float* __restrict__ iW2, const float* __restrict__ ib2,
    const float* __restrict__ vW1, const float* __restrict__ vb1,
    const float* __restrict__ vW2, const float* __restrict__ vb2,
    const float* __restrict__ cW1, const float* __restrict__ cb1,
    const float* __restrict__ cW2, const float* __restrict__ cb2,
    const float* __restrict__ rW, const float* __restrict__ rb,
    float* __restrict__ out)
{
  const int b    = blockIdx.x;
  const int l    = threadIdx.x;
  const int h16  = l & 15;
  const int p    = (l >> 4) & 1;
  const int hf   = l >> 2;           // quad Q == y index held
  const int d0   = (2 * l) & 7;
  const int q4   = 4 * (l & 3);      // f-quartet base (s_f columns)
  const int ixA = 4 * (l ^ 16);      // y[Q^4]
  const int ixB = 4 * (l ^ 20);      // y[Q^5]
  const int ixC = 4 * (l ^ 24);      // y[Q^6]
  const int ixD = 4 * (l ^ 28);      // y[Q^7]
  const int ywslot = ((l & 3) == 0) ? (64 + hf) : (80 + l);  // final y publish

  __shared__ __align__(16) float sbuf[16];    // init relu staging
  __shared__ __align__(16) float cbuf[160];   // [0..63] s, [64..79] y, [80..143] dump
  __shared__ __align__(16) float xbuf[1040];  // 2 x 64 dx-rows (8 floats) + pad

  const float* __restrict__ ysb = ys + (size_t)b * (T_LEN * 8);

  const float NL2E = -1.4426950408889634f;                 // -log2(e)
  const float TSW  = 2.0f * 1.4426950408889634f * 0.909f;  // weight scale (tanh arg)
  const float TSB  = 2.0f * 1.4426950408889634f;           // bias scale (tanh arg)

  // ---- per-lane weights (scaled) ----
  float w1t, b1m;
  float Wy[8];
  {
    const float* W1 = p ? cW1 : vW1;
    const float* bv = p ? cb1 : vb1;
    w1t = NL2E * W1[h16 * 17];
    b1m = NL2E * bv[h16];
    const int Q = l >> 2;
#pragma unroll
    for (int j = 0; j < 8; ++j)
      Wy[j] = NL2E * W1[h16 * 17 + 1 + (Q ^ j)];
    if (l >= 32) { w1t = 0.0f; b1m = 0.0f; }  // t/bias counted once (low half)
  }
  v2f W2q[2];
#pragma unroll
  for (int j = 0; j < 2; ++j) {
    v2f w; w.x = TSW * vW2[hf * 16 + q4 + 2 * j];
           w.y = TSW * vW2[hf * 16 + q4 + 2 * j + 1];
    W2q[j] = w;
  }
  v2f G0p[8], G1p[8];
#pragma unroll
  for (int k = 0; k < 8; ++k) {
    v2f c0; c0.x = TSW * cW2[(2 * l) * 16 + 2 * k]; c0.y = TSW * cW2[(2 * l) * 16 + 2 * k + 1];
    G0p[k] = c0;
    v2f c1; c1.x = TSW * cW2[(2 * l + 1) * 16 + 2 * k]; c1.y = TSW * cW2[(2 * l + 1) * 16 + 2 * k + 1];
    G1p[k] = c1;
  }
  v2f bg0v; bg0v.x = TSB * cb2[2 * l];     bg0v.y = 0.0f;   // g row 2l bias
  v2f bg1v; bg1v.x = TSB * cb2[2 * l + 1]; bg1v.y = 0.0f;   // g row 2l+1 bias
  v2f bfv;  bfv.x  = 0.25f * TSB * vb2[hf]; bfv.y = 0.0f;   // f bias / 4

  const float t0 = ts[0];

  // ---- initial hidden state (cold path, via LDS; same-wave DS is ordered) ----
  float y_own;
  {
    float acc = ib1[h16] + iW1[h16 * 9] * t0;
#pragma unroll
    for (int d = 0; d < 8; ++d) acc = fmaf(iW1[h16 * 9 + 1 + d], ysb[d], acc);
    sbuf[h16] = fmaxf(acc, 0.0f);
    cfence();
    float acc2 = ib2[h16];
#pragma unroll
    for (int k = 0; k < 16; ++k) acc2 = fmaf(iW2[h16 * 16 + k], sbuf[k], acc2);
    cbuf[64 + h16] = acc2;     // duplicate same-addr same-value writes (init only)
    cfence();
    y_own = cbuf[64 + hf];     // quad-replicated y[Q]
  }

  // ---- readout at t0 ----
  {
    const float o = readout_lds(cbuf, rW, rb[0]);
    if (l == 0) out[2 * b] = o;
  }

  // ---- dx staging: 64-row chunks, double-buffered, prefetch next chunk ----
  const int CLAMP = T_LEN * 8 - 4;
  float4 A, Bq, Cq, Dq;
  {
    const int f0 = l * 8;
    A  = *(const float4*)(ysb + min(f0,      CLAMP));
    Bq = *(const float4*)(ysb + min(f0 + 4,  CLAMP));
    Cq = *(const float4*)(ysb + min(f0 + 8,  CLAMP));
    Dq = *(const float4*)(ysb + min(f0 + 12, CLAMP));
    float4 e0, e1;
    e0.x = Cq.x - A.x;  e0.y = Cq.y - A.y;  e0.z = Cq.z - A.z;  e0.w = Cq.w - A.w;
    e1.x = Dq.x - Bq.x; e1.y = Dq.y - Bq.y; e1.z = Dq.z - Bq.z; e1.w = Dq.w - Bq.w;
    *(float4*)(xbuf + l * 8)     = e0;
    *(float4*)(xbuf + l * 8 + 4) = e1;
    cfence();
  }

  // ---- prime pipelined state: dx + y-gather ----
  v2f dxc = *(const v2f*)(xbuf + d0);
  float yg1 = dpp_movf<0x141>(y_own);  // y[Q^1]
  float yg2 = dpp_movf<0x128>(y_own);  // y[Q^2] (lane^8)
  float yg3 = dpp_movf<0x140>(y_own);  // y[Q^3]
  float yg4 = bperm(ixA, y_own);       // y[Q^4]
  float yg5 = bperm(ixB, y_own);       // y[Q^5]
  float yg6 = bperm(ixC, y_own);       // y[Q^6]
  float yg7 = bperm(ixD, y_own);       // y[Q^7]
  float t = t0;

  // ---- one simulation step (macro so unrolled bodies stay register-clean) ----
#define STEP(XB, JNEXT)                                                        \
  {                                                                            \
    const v2f dx = dxc;                                                        \
    const float m_t = fmaf(w1t, t, b1m);                                       \
    float aca = fmaf(Wy[0], y_own, m_t);                                       \
    float acb = Wy[1] * yg1;                                                   \
    aca = fmaf(Wy[2], yg2, aca);                                               \
    acb = fmaf(Wy[3], yg3, acb);                                               \
    aca = fmaf(Wy[4], yg4, aca);                                               \
    acb = fmaf(Wy[5], yg5, acb);                                               \
    aca = fmaf(Wy[6], yg6, aca);                                               \
    acb = fmaf(Wy[7], yg7, acb);                                               \
    const float m = half_sum(aca + acb);                                       \
    const float eM = fexp2(m);                                                 \
    const float s  = (m * NLN2f) * frcp(1.0f + eM);                            \
    cbuf[l] = s;                                                               \
    cfence();                                                                  \
    const v4f g0 = *(const v4f*)(cbuf + 16);                                   \
    const v4f g1 = *(const v4f*)(cbuf + 20);                                   \
    const v4f g2 = *(const v4f*)(cbuf + 24);                                   \
    const v4f g3 = *(const v4f*)(cbuf + 28);                                   \
    const v4f sf = *(const v4f*)(cbuf + q4);                                   \
    v2f ga = pk_fma_nv(G0p[0], g0.xy, bg0v);                                   \
    v2f gb = pk_fma_nv(G1p[0], g0.xy, bg1v);                                   \
    v2f gc = pk_mul_v(G0p[4], g2.xy);                                          \
    v2f gd = pk_mul_v(G1p[4], g2.xy);                                          \
    pk_fma_v(ga, G0p[1], g0.zw); pk_fma_v(gb, G1p[1], g0.zw);                  \
    pk_fma_v(ga, G0p[2], g1.xy); pk_fma_v(gb, G1p[2], g1.xy);                  \
    pk_fma_v(ga, G0p[3], g1.zw); pk_fma_v(gb, G1p[3], g1.zw);                  \
    pk_fma_v(gc, G0p[5], g2.zw); pk_fma_v(gd, G1p[5], g2.zw);                  \
    pk_fma_v(gc, G0p[6], g3.xy); pk_fma_v(gd, G1p[6], g3.xy);                  \
    pk_fma_v(gc, G0p[7], g3.zw); pk_fma_v(gd, G1p[7], g3.zw);                  \
    v2f fa = pk_fma_nv(W2q[0], sf.xy, bfv);                                    \
    pk_fma_v(fa, W2q[1], sf.zw);                                               \
    float fp = fa.x + fa.y;                                                    \
    fp = dpp_add<0xB1>(fp);                                                    \
    fp = dpp_add<0x4E>(fp);                                                    \
    const v2f gs0 = pk_add_v(ga, gc);                                          \
    const v2f gs1 = pk_add_v(gb, gd);                                          \
    const float g0v = fmaf(-2.0f, frcp(1.0f + fexp2(gs0.x + gs0.y)), 1.0f);    \
    const float g1v = fmaf(-2.0f, frcp(1.0f + fexp2(gs1.x + gs1.y)), 1.0f);    \
    const float fv  = fmaf(-2.0f, frcp(1.0f + fexp2(fp)), 1.0f);               \
    float pr = fmaf(g0v, dx.x, g1v * dx.y);                                    \
    pr = dpp_add<0xB1>(pr);                                                    \
    pr = dpp_add<0x4E>(pr);                                                    \
    y_own = y_own + (fv + pr);                                                 \
    dxc = *(const v2f*)((XB) + (JNEXT) * 8 + d0);                              \
    yg1 = dpp_movf<0x141>(y_own);                                              \
    yg2 = dpp_movf<0x128>(y_own);                                              \
    yg3 = dpp_movf<0x140>(y_own);                                              \
    yg4 = bperm(ixA, y_own);                                                   \
    yg5 = bperm(ixB, y_own);                                                   \
    yg6 = bperm(ixC, y_own);                                                   \
    yg7 = bperm(ixD, y_own);                                                   \
    t += 1.0f;                                                                 \
  }

  // ---- chunks 0..62: constant 64 steps, unrolled x4 ----
  for (int c = 0; c < 63; ++c) {
    {
      const int f0 = (c + 1) * 512 + l * 8;
      A  = *(const float4*)(ysb + min(f0,      CLAMP));
      Bq = *(const float4*)(ysb + min(f0 + 4,  CLAMP));
      Cq = *(const float4*)(ysb + min(f0 + 8,  CLAMP));
      Dq = *(const float4*)(ysb + min(f0 + 12, CLAMP));
    }
    const float* __restrict__ xb = xbuf + (c & 1) * 512;
#pragma unroll 4
    for (int j = 0; j < 64; ++j) {
      STEP(xb, j + 1)   // j+1==64 reads pad/other buffer; corrected below
    }
    float* xbn = xbuf + ((c + 1) & 1) * 512;
    float4 e0, e1;
    e0.x = Cq.x - A.x;  e0.y = Cq.y - A.y;  e0.z = Cq.z - A.z;  e0.w = Cq.w - A.w;
    e1.x = Dq.x - Bq.x; e1.y = Dq.y - Bq.y; e1.z = Dq.z - Bq.z; e1.w = Dq.w - Bq.w;
    *(float4*)(xbn + l * 8)     = e0;
    *(float4*)(xbn + l * 8 + 4) = e1;
    cfence();
    dxc = *(const v2f*)(xbn + d0);   // correct first-step dx of next chunk
  }
  // ---- tail chunk 63: 63 steps (rows 4032..4094) ----
  {
    const float* __restrict__ xb = xbuf + 512;  // chunk 63 buffer (63&1 = 1)
    for (int j = 0; j < 63; ++j) {
      STEP(xb, min(j + 1, 63))
    }
  }
#undef STEP

  // ---- publish final y once, then readout at t1 ----
  cbuf[ywslot] = y_own;     // (l&3)==0 lanes -> real slots, rest -> dump region
  cfence();
  {
    const float o = readout_lds(cbuf, rW, rb[0]);
    if (l == 0) out[2 * b + 1] = o;
  }
}

extern "C" void kernel_launch(void* const* d_in, const int* in_sizes, int n_in,
                              void* d_out, int out_size, void* d_ws, size_t ws_size,
                              hipStream_t stream) {
  (void)in_sizes; (void)n_in; (void)out_size; (void)d_ws; (void)ws_size;
  const float* ts  = (const float*)d_in[0];
  const float* ys  = (const float*)d_in[1];
  const float* iW1 = (const float*)d_in[2];
  const float* ib1 = (const float*)d_in[3];
  const float* iW2 = (const float*)d_in[4];
  const float* ib2 = (const float*)d_in[5];
  const float* vW1 = (const float*)d_in[6];
  const float* vb1 = (const float*)d_in[7];
  const float* vW2 = (const float*)d_in[8];
  const float* vb2 = (const float*)d_in[9];
  const float* cW1 = (const float*)d_in[10];
  const float* cb1 = (const float*)d_in[11];
  const float* cW2 = (const float*)d_in[12];
  const float* cb2 = (const float*)d_in[13];
  const float* rW  = (const float*)d_in[14];
  const float* rb  = (const float*)d_in[15];
  float* out = (float*)d_out;
  hipLaunchKernelGGL(disc_kernel, dim3(512), dim3(64), 0, stream,
                     ts, ys, iW1, ib1, iW2, ib2, vW1, vb1, vW2, vb2,
                     cW1, cb1, cW2, cb2, rW, rb, out);
}